// Round 11
// baseline (706.140 us; speedup 1.0000x reference)
//
#include <hip/hip_runtime.h>
#include <math.h>

#define DD 512
#define NS 258
#define NSP 264
#define NWG 64
#define BLK 1024
#define RHO_ 100.0
#define SIG_ 1e-3
#define NITER 150
#define DELTA0 (3969.0 + SIG_ + RHO_)

typedef float v2f __attribute__((ext_vector_type(2)));

// ---------------- workspace byte offsets ----------------
#define OFF_E1     512u        // double[64*512]
#define OFF_SUMS   512u        // double[456] (alias e1; written after e1 dead)
#define OFF_INV    4608u       // double[66*67] (alias e1)
#define OFF_E2     262656u     // double[64*512]
#define OFF_P      524800u     // double[4096]
#define OFF_W      557568u     // double[4096]
#define OFF_P32    590336u     // float[4096]
#define OFF_W32    606720u     // float[4096]
#define OFF_KSA    623104u     // double[258*264]
#define OFF_KSB    1168000u    // double[258*264]
#define OFF_N32    1712896u    // float[258*264] permuted admm ordering

// permutation: GJ ordering [E',F',g'(128),g(129),E(130..193),F(194..257)]
//          ->  admm ordering [E'(0..63),F'(64..127),E(128..191),F(192..255),g'(256),g(257)]
__device__ __forceinline__ int perm258(int i){
  return (i < 128) ? i : (i == 128) ? 256 : (i == 129) ? 257 : (i - 2);
}

// ---------------- DPP reduction helpers (fp32, VALU pipe) ----------------
template<int CTRL>
__device__ __forceinline__ float dppadd(float v){
  int t = __builtin_amdgcn_mov_dpp(__float_as_int(v), CTRL, 0xF, 0xF, 1);
  return v + __int_as_float(t);
}
template<int CTRL>
__device__ __forceinline__ float dppmax(float v){
  int t = __builtin_amdgcn_mov_dpp(__float_as_int(v), CTRL, 0xF, 0xF, 1);
  return fmaxf(v, __int_as_float(t));
}
__device__ __forceinline__ float sum16(float v){
  v = dppadd<0xB1>(v);   // quad_perm xor1
  v = dppadd<0x4E>(v);   // quad_perm xor2
  v = dppadd<0x124>(v);  // row_ror:4
  v = dppadd<0x128>(v);  // row_ror:8
  return v;
}
__device__ __forceinline__ float wsum64f(float v){
  v = sum16(v);
  v += __shfl_xor(v, 16, 64);
  v += __shfl_xor(v, 32, 64);
  return v;
}
// all-VALU wave reduction -> uniform scalar
__device__ __forceinline__ float wsum64u(float v){
  v = sum16(v);
  v = dppadd<0x142>(v);  // row_bcast15
  v = dppadd<0x143>(v);  // row_bcast31
  return __uint_as_float(__builtin_amdgcn_readlane(__float_as_uint(v), 63));
}
__device__ __forceinline__ float wmax64f(float v){
  v = dppmax<0xB1>(v); v = dppmax<0x4E>(v); v = dppmax<0x124>(v); v = dppmax<0x128>(v);
  v = fmaxf(v, __shfl_xor(v, 16, 64));
  v = fmaxf(v, __shfl_xor(v, 32, 64));
  return v;
}

// ---------------- f64 shuffle reductions ----------------
__device__ __forceinline__ double gsum16d(double v){
  v += __shfl_xor(v, 1, 64);
  v += __shfl_xor(v, 2, 64);
  v += __shfl_xor(v, 4, 64);
  v += __shfl_xor(v, 8, 64);
  return v;
}
__device__ __forceinline__ double wsum64d(double v){
  v = gsum16d(v);
  v += __shfl_xor(v, 16, 64);
  v += __shfl_xor(v, 32, 64);
  return v;
}

// ---- Ksmall index decode: order [E'(0..63), F'(64..127), g'(128), g(129), E(130..193), F(194..257)]
__device__ __forceinline__ void decode_idx(int t, int& cls, int& pr, int& ix){
  if (t < 64)       { cls = 1; pr = 1; ix = t; }
  else if (t < 128) { cls = 2; pr = 1; ix = t - 64; }
  else if (t == 128){ cls = 0; pr = 1; ix = 0; }
  else if (t == 129){ cls = 0; pr = 0; ix = 0; }
  else if (t < 194) { cls = 1; pr = 0; ix = t - 130; }
  else              { cls = 2; pr = 0; ix = t - 194; }
}

// ---- closed-form K_small(r,c) ----
__device__ __forceinline__ double ksval(int r, int c, const double* __restrict__ p,
                                        const double* __restrict__ w, const double* sumsL){
  int cr, prr, ir, cc, prc, ic;
  decode_idx(r, cr, prr, ir);
  decode_idx(c, cc, prc, ic);
  int m = prr + prc;
  double tval;
  if (cr == 0 && cc == 0)      tval = sumsL[m];
  else if (cr == 0 && cc == 1) tval = sumsL[8 + m*64 + ic];
  else if (cr == 1 && cc == 0) tval = sumsL[8 + m*64 + ir];
  else if (cr == 0 && cc == 2) tval = sumsL[200 + m*64 + ic];
  else if (cr == 2 && cc == 0) tval = sumsL[200 + m*64 + ir];
  else if (cr == 1 && cc == 1) tval = (ir == ic) ? sumsL[8 + m*64 + ir] : 0.0;
  else if (cr == 2 && cc == 2) tval = (ir == ic) ? sumsL[200 + m*64 + ir] : 0.0;
  else if (cr == 1 && cc == 2){
    double wv = w[ic*64 + ir], pv = p[ic*64 + ir];
    tval = (m == 0) ? wv : (m == 1) ? wv*pv : wv*pv*pv;
  } else {
    double wv = w[ir*64 + ic], pv = p[ir*64 + ic];
    tval = (m == 0) ? wv : (m == 1) ? wv*pv : wv*pv*pv;
  }
  double mv2 = 0.0;
  if (cr == 0 && cc == 0 && prr != prc) mv2 = -2.0;
  if (cr != 0 && cr == cc && ir == ic){
    if (prr != prc) mv2 = 2.0;
    else if (prr == 1) mv2 = -4.0 * RHO_;
  }
  return tval + mv2;
}

// =================== KP1: features (coalesced W-matvec) ===================
__global__ __launch_bounds__(BLK) void kp_feat(const float* __restrict__ ft,
                                               const float* __restrict__ fd,
                                               const float* __restrict__ iou,
                                               const float* __restrict__ Wm,
                                               const float* __restrict__ bb,
                                               char* ws){
  double* e1 = (double*)(ws + OFF_E1);
  double* e2 = (double*)(ws + OFF_E2);
  __shared__ double SH[2216];   // 17.7 KB
  const int tid  = threadIdx.x;
  const int wg   = blockIdx.x;
  const int lane = tid & 63;
  const int wv   = tid >> 6;
  float* ftR = (float*)SH;          // 512 f
  float* fdR = ftR + 512;           // 512 f
  float* u1R = fdR + 512;           // 512 f
  float* u2R = u1R + 512;           // 512 f
  double* m0r = SH + 1024;          // 64
  double* m0c = m0r + 64;           // 64
  double* wp  = m0c + 64;           // 32
  double* sca = wp + 32;            // 8
  double* vbuf = SH + 1192;         // 1024
  const int i = wg;
  if (tid < 512){ ftR[tid] = ft[i*DD + tid]; fdR[tid] = fd[i*DD + tid]; }
  {
    double nf = 0.0, nd = 0.0;
    if (tid < 512){
      float a = ftR[tid], b = fdR[tid];
      nf = (double)a*a; nd = (double)b*b;
    }
    nf = wsum64d(nf); nd = wsum64d(nd);
    if (lane == 0){ wp[wv] = nf; wp[16 + wv] = nd; }
    __syncthreads();
    if (tid == 0){
      double s0 = 0, s1 = 0;
      for (int q = 0; q < 16; ++q){ s0 += wp[q]; s1 += wp[16+q]; }
      sca[0] = s0; sca[1] = s1;
    }
  }
  {
    int j = tid >> 4, sub = tid & 15;
    double ar = 0.0, ac = 0.0;
    for (int t2 = 0; t2 < 32; ++t2){
      int k = t2*16 + sub;
      ar += (double)ftR[k] * (double)fd[(size_t)j*DD + k];
      ac += (double)fdR[k] * (double)ft[(size_t)j*DD + k];
    }
    ar = gsum16d(ar); ac = gsum16d(ac);
    if (sub == 0){
      m0r[j] = ar + (double)iou[i*64 + j];
      m0c[j] = ac + (double)iou[j*64 + i];
    }
  }
  __syncthreads();
  {
    int c = tid & 511, half = tid >> 9;
    const double* m0 = half ? m0c : m0r;
    const float*  FB = half ? ft  : fd;
    double a0 = 0, b0 = 0, c0 = 0, d0 = 0;
    for (int a2 = 0; a2 < 64; a2 += 4){
      a0 += m0[a2]   * (double)FB[(size_t)(a2  )*DD + c];
      b0 += m0[a2+1] * (double)FB[(size_t)(a2+1)*DD + c];
      c0 += m0[a2+2] * (double)FB[(size_t)(a2+2)*DD + c];
      d0 += m0[a2+3] * (double)FB[(size_t)(a2+3)*DD + c];
    }
    double mv = (a0 + b0) + (c0 + d0);
    double nn = wsum64d(mv*mv);
    if (lane == 0) wp[wv] = nn;
    __syncthreads();
    if (tid < 2){
      double s = 0;
      for (int q = tid*8; q < tid*8 + 8; ++q) s += wp[q];
      sca[2 + tid] = sqrt(sca[tid] / s);
    }
    __syncthreads();
    double l = sca[2 + half];
    float* uR = half ? u2R : u1R;
    const float* fR = half ? fdR : ftR;
    uR[c] = (float)((double)fR[c] + l*mv);
  }
  __syncthreads();
  // e = l2norm(relu(u @ W.T + b)) — 16-lane group per output row (coalesced W)
  {
    const int g16 = tid >> 4;          // group -> output row
    const int sub = tid & 15;
    for (int pass = 0; pass < 16; ++pass){
      int c_all = pass*64 + g16;       // 0..1023
      int c = c_all & 511, half = c_all >> 9;
      const float* uR  = half ? u2R : u1R;
      const float* wrp = Wm + (size_t)c*DD;
      double acc = 0.0;
#pragma unroll
      for (int j = 0; j < 8; ++j){
        int k = sub*4 + j*64;
        float4 wq = *(const float4*)(wrp + k);
        float4 uq = *(const float4*)(uR + k);
        acc += (double)uq.x*wq.x + (double)uq.y*wq.y + (double)uq.z*wq.z + (double)uq.w*wq.w;
      }
      acc = gsum16d(acc);
      if (sub == 0) vbuf[c_all] = fmax(acc + (double)bb[c], 0.0);
    }
    __syncthreads();
    double v = vbuf[tid];
    double nn = wsum64d(v*v);
    if (lane == 0) wp[wv] = nn;
    __syncthreads();
    if (tid < 2){
      double s = 0;
      for (int q = tid*8; q < tid*8 + 8; ++q) s += wp[q];
      sca[4 + tid] = 1.0 / fmax(sqrt(s), 1e-12);
    }
    __syncthreads();
    int c = tid & 511, half = tid >> 9;
    double* e = half ? e2 : e1;
    e[(size_t)i*DD + c] = v * sca[4 + half];
  }
}

// =================== KP2: p/w ===================
__global__ __launch_bounds__(BLK) void kp_pw(char* ws){
  const double* e1 = (const double*)(ws + OFF_E1);
  const double* e2 = (const double*)(ws + OFF_E2);
  double* p   = (double*)(ws + OFF_P);
  double* w   = (double*)(ws + OFF_W);
  float*  p32 = (float*) (ws + OFF_P32);
  float*  w32 = (float*) (ws + OFF_W32);
  __shared__ double e2R[512];
  const int tid = threadIdx.x;
  const int a = blockIdx.x;
  if (tid < 512) e2R[tid] = e2[(size_t)a*DD + tid];
  __syncthreads();
  int b = tid >> 4, sub = tid & 15;
  double a0 = 0.0, a1 = 0.0;
  for (int t2 = 0; t2 < 32; t2 += 2){
    a0 += e1[(size_t)b*DD + t2*16 + sub]     * e2R[t2*16 + sub];
    a1 += e1[(size_t)b*DD + (t2+1)*16 + sub] * e2R[(t2+1)*16 + sub];
  }
  double acc = gsum16d(a0 + a1);
  if (sub == 0){
    double pv = acc;
    double wv2 = 1.0 / (DELTA0 - pv);
    int jj = a*64 + b;
    p[jj] = pv; w[jj] = wv2; p32[jj] = (float)pv; w32[jj] = (float)wv2;
  }
}

// =================== KP3: sums + invd -> global ===================
__global__ __launch_bounds__(BLK) void kp_sums(char* ws){
  const double* p = (const double*)(ws + OFF_P);
  const double* w = (const double*)(ws + OFF_W);
  double* sumsG = (double*)(ws + OFF_SUMS);
  __shared__ double sumsL[456];
  const int tid = threadIdx.x;
  int a = tid >> 4, sub = tid & 15;
  {
    double r0 = 0, r1 = 0, r2 = 0;
    for (int b = sub*4; b < sub*4 + 4; ++b){
      double wv = w[a*64 + b], pv = p[a*64 + b];
      r0 += wv; r1 += wv*pv; r2 += wv*pv*pv;
    }
    r0 = gsum16d(r0); r1 = gsum16d(r1); r2 = gsum16d(r2);
    if (sub == 0){ sumsL[200 + a] = r0; sumsL[264 + a] = r1; sumsL[328 + a] = r2; }
  }
  {
    int b2 = tid >> 4;
    double c0 = 0, c1 = 0, c2 = 0;
    for (int a2 = sub*4; a2 < sub*4 + 4; ++a2){
      double wv = w[a2*64 + b2], pv = p[a2*64 + b2];
      c0 += wv; c1 += wv*pv; c2 += wv*pv*pv;
    }
    c0 = gsum16d(c0); c1 = gsum16d(c1); c2 = gsum16d(c2);
    if (sub == 0){ sumsL[8 + b2] = c0; sumsL[72 + b2] = c1; sumsL[136 + b2] = c2; }
  }
  __syncthreads();
  if (tid == 0){
    double t0 = 0, t1 = 0, t2 = 0;
    for (int a3 = 0; a3 < 64; ++a3){
      t0 += sumsL[200 + a3]; t1 += sumsL[264 + a3]; t2 += sumsL[328 + a3];
    }
    sumsL[0] = t0; sumsL[1] = t1; sumsL[2] = t2;
    sumsL[3] = 0; sumsL[4] = 0; sumsL[5] = 0; sumsL[6] = 0; sumsL[7] = 0;
  }
  if (tid >= 64 && tid < 128){
    int k = tid - 64;
    sumsL[392 + k] = 1.0 / (sumsL[136 + k] - 4.0*RHO_);   // E' diag closed form
  }
  __syncthreads();
  for (int idx = tid; idx < 456; idx += BLK) sumsG[idx] = sumsL[idx];
}

// =================== KP4: specialized fused pivot-1 -> KsB (258 WGs, 4-way row split) ===================
__global__ __launch_bounds__(BLK) void kp_p3(char* ws){
  const double* p = (const double*)(ws + OFF_P);
  const double* w = (const double*)(ws + OFF_W);
  const double* sumsG = (const double*)(ws + OFF_SUMS);
  double* KsB = (double*)(ws + OFF_KSB);
  __shared__ double sumsL[456];
  __shared__ double temp[68];
  const int tid = threadIdx.x;
  const int c = blockIdx.x;
  for (int idx = tid; idx < 456; idx += BLK) sumsL[idx] = sumsG[idx];
  __syncthreads();
  const double* invd = sumsL + 392;
  if (tid < 64){
    int k = tid;
    temp[k] = (c < 64) ? ((k == c) ? invd[k] : 0.0) : ksval(k, c, p, w, sumsL) * invd[k];
  }
  __syncthreads();
  const double* tp = temp;
  const int s = tid & 3;
  auto dorow = [&](int rr){
    if (rr < 64){
      if (s == 0) KsB[(size_t)rr*NSP + c] = tp[rr];
      return;
    }
    double acc = 0.0;
    if (rr < 128){
      const double* wr_ = w + (rr-64)*64;
      const double* pr_ = p + (rr-64)*64;
      for (int k = s; k < 64; k += 4){ double pv = pr_[k]; acc += wr_[k]*pv*pv*tp[k]; }
    } else if (rr == 128){
      for (int k = s; k < 64; k += 4) acc += sumsL[136 + k]*tp[k];
    } else if (rr == 129){
      for (int k = s; k < 64; k += 4) acc += sumsL[72 + k]*tp[k];
    } else if (rr < 194){
      if (s == 0){ int ir = rr - 130; acc = (sumsL[72 + ir] + 2.0)*tp[ir]; }
    } else {
      int ir = rr - 194;
      const double* wr_ = w + ir*64;
      const double* pr_ = p + ir*64;
      for (int k = s; k < 64; k += 4) acc += wr_[k]*pr_[k]*tp[k];
    }
    acc += __shfl_xor(acc, 1, 64);
    acc += __shfl_xor(acc, 2, 64);
    if (s == 0){
      double first = (c < 64) ? 0.0 : ksval(rr, c, p, w, sumsL);
      KsB[(size_t)rr*NSP + c] = first - acc;
    }
  };
  { int r = tid >> 2; if (r < 256) dorow(r); }
  if (tid < 8) dorow(256 + (tid >> 2));
}

// =================== KP-inv: rank-4 blocked GJ, branch-free ===================
// Stage A: verified rank-2 staging (pivots k,k+1) from pristine M0.
// Stage B: rank-2 staging for (k+2,k+3) against M2 = M0 - CV1⊗RV1 - CV2⊗RV2,
//          computed ON THE FLY (M never touched between stages).
// Update:  one fused pass M -= Σ_{m=1..4} CVm⊗RVm  (exact blocked elimination).
// 3 barriers / 4 pivots; full-matrix passes halve vs rank-2.
template<int MM>
__global__ __launch_bounds__(BLK) void kp_inv(const double* __restrict__ src, int p0,
                                              double* __restrict__ invG){
  __shared__ double M[MM*67];
  __shared__ double RV1[MM], RV2[MM], RV3[MM], RV4[MM];
  __shared__ double CV1[MM], CV2[MM], CV3[MM], CV4[MM];
  const int tid = threadIdx.x;
  const int lane = tid & 63, wv = tid >> 6;
  for (int idx = tid; idx < MM*MM; idx += BLK)
    M[(idx/MM)*67 + (idx%MM)] = src[(size_t)(p0 + idx/MM)*NSP + p0 + idx%MM];
  __syncthreads();
  constexpr int K4 = (MM/4)*4;
  for (int k = 0; k < K4; k += 4){
    // ---- stage A: pivots (k,k+1) ----
    if (tid < MM){
      int j = tid;
      double pk  = 1.0 / M[k*67 + k];
      double ck1 = M[(k+1)*67 + k];
      double rv  = M[k*67 + j] * pk;
      if (j == k) rv += pk;
      double rk1 = M[k*67 + k+1] * pk;
      double q   = 1.0 / (M[(k+1)*67 + k+1] - ck1*rk1);
      double r2  = (M[(k+1)*67 + j] - ck1*rv) * q;
      if (j == k+1) r2 += q;
      RV1[j] = rv; RV2[j] = r2;
    } else if (tid >= 512 && tid < 512 + MM){
      int i = tid - 512;
      double pk  = 1.0 / M[k*67 + k];
      double rk1 = M[k*67 + k+1] * pk;
      double cv  = M[i*67 + k];
      if (i == k) cv -= 1.0;
      double c2  = M[i*67 + k+1] - cv*rk1;
      if (i == k+1) c2 -= 1.0;
      CV1[i] = cv; CV2[i] = c2;
    }
    __syncthreads();
    // ---- stage B: pivots (a,b) = (k+2,k+3) on M2 (on the fly) ----
    {
      const int a = k+2, b = k+3;
      if (tid < MM){
        int j = tid;
        double cv1a = CV1[a], cv2a = CV2[a], cv1b = CV1[b], cv2b = CV2[b];
        double rv1a = RV1[a], rv2a = RV2[a], rv1b = RV1[b], rv2b = RV2[b];
        double pk3 = 1.0 / (M[a*67 + a] - cv1a*rv1a - cv2a*rv2a);
        double ck3 = M[b*67 + a] - cv1b*rv1a - cv2b*rv2a;
        double m_aj = M[a*67 + j] - cv1a*RV1[j] - cv2a*RV2[j];
        double rv3 = m_aj * pk3;
        if (j == a) rv3 += pk3;
        double rk3 = (M[a*67 + b] - cv1a*rv1b - cv2a*rv2b) * pk3;
        double Mbb = M[b*67 + b] - cv1b*rv1b - cv2b*rv2b;
        double q3 = 1.0 / (Mbb - ck3*rk3);
        double m_bj = M[b*67 + j] - cv1b*RV1[j] - cv2b*RV2[j];
        double rv4 = (m_bj - ck3*rv3) * q3;
        if (j == b) rv4 += q3;
        RV3[j] = rv3; RV4[j] = rv4;
      } else if (tid >= 512 && tid < 512 + MM){
        int i = tid - 512;
        double cv1a = CV1[a], cv2a = CV2[a];
        double rv1a = RV1[a], rv2a = RV2[a], rv1b = RV1[b], rv2b = RV2[b];
        double pk3 = 1.0 / (M[a*67 + a] - cv1a*rv1a - cv2a*rv2a);
        double rk3 = (M[a*67 + b] - cv1a*rv1b - cv2a*rv2b) * pk3;
        double cv1i = CV1[i], cv2i = CV2[i];
        double cv3 = M[i*67 + a] - cv1i*rv1a - cv2i*rv2a;
        if (i == a) cv3 -= 1.0;
        double m_ib = M[i*67 + b] - cv1i*rv1b - cv2i*rv2b;
        double cv4 = m_ib - cv3*rk3;
        if (i == b) cv4 -= 1.0;
        CV3[i] = cv3; CV4[i] = cv4;
      }
    }
    __syncthreads();
    // ---- fused rank-4 update ----
    {
      double r1l = RV1[lane], r2l = RV2[lane], r3l = RV3[lane], r4l = RV4[lane];
      const bool hi = (lane + 64) < MM;
      double r1h = hi ? RV1[lane+64] : 0.0, r2h = hi ? RV2[lane+64] : 0.0;
      double r3h = hi ? RV3[lane+64] : 0.0, r4h = hi ? RV4[lane+64] : 0.0;
      for (int i = wv; i < MM; i += 16){
        double c1 = CV1[i], c2 = CV2[i], c3 = CV3[i], c4 = CV4[i];
        M[i*67 + lane] -= (c1*r1l + c2*r2l) + (c3*r3l + c4*r4l);
        if (hi) M[i*67 + lane + 64] -= (c1*r1h + c2*r2h) + (c3*r3h + c4*r4h);
      }
    }
    __syncthreads();
  }
  // ---- tail (MM=66): final 2 pivots via rank-2 ----
  if constexpr (K4 < MM){
    const int k = K4;
    if (tid < MM){
      int j = tid;
      double pk  = 1.0 / M[k*67 + k];
      double ck1 = M[(k+1)*67 + k];
      double rv  = M[k*67 + j] * pk;
      if (j == k) rv += pk;
      double rk1 = M[k*67 + k+1] * pk;
      double q   = 1.0 / (M[(k+1)*67 + k+1] - ck1*rk1);
      double r2  = (M[(k+1)*67 + j] - ck1*rv) * q;
      if (j == k+1) r2 += q;
      RV1[j] = rv; RV2[j] = r2;
    } else if (tid >= 512 && tid < 512 + MM){
      int i = tid - 512;
      double pk  = 1.0 / M[k*67 + k];
      double rk1 = M[k*67 + k+1] * pk;
      double cv  = M[i*67 + k];
      if (i == k) cv -= 1.0;
      double c2  = M[i*67 + k+1] - cv*rk1;
      if (i == k+1) c2 -= 1.0;
      CV1[i] = cv; CV2[i] = c2;
    }
    __syncthreads();
    {
      double r1l = RV1[lane], r2l = RV2[lane];
      const bool hi = (lane + 64) < MM;
      double r1h = hi ? RV1[lane+64] : 0.0, r2h = hi ? RV2[lane+64] : 0.0;
      for (int i = wv; i < MM; i += 16){
        double c1 = CV1[i], c2 = CV2[i];
        M[i*67 + lane] -= c1*r1l + c2*r2l;
        if (hi) M[i*67 + lane + 64] -= c1*r1h + c2*r2h;
      }
    }
    __syncthreads();
  }
  for (int idx = tid; idx < MM*MM; idx += BLK)
    invG[(idx/MM)*67 + idx%MM] = M[(idx/MM)*67 + idx%MM];
}

// =================== KP-apply: Schur update (258 WGs, split dots) ===================
template<int MM>
__global__ __launch_bounds__(BLK) void kp_apply(const double* __restrict__ src,
                                                double* __restrict__ dstD,
                                                float* __restrict__ dstF, int p0,
                                                const double* __restrict__ invG){
  __shared__ double M[4422];
  __shared__ double temp[68];
  __shared__ double srcMid[66];
  const int tid = threadIdx.x;
  const int c = blockIdx.x;
  for (int idx = tid; idx < MM*67; idx += BLK) M[idx] = invG[idx];
  if (tid < MM) srcMid[tid] = src[(size_t)(p0 + tid)*NSP + c];
  __syncthreads();
  const bool cpiv = (c >= p0 && c < p0 + MM);
  if (cpiv){
    if (tid < MM) temp[tid] = M[tid*67 + (c - p0)];
  } else {
    int k = tid >> 3, s8 = tid & 7;
    if (k < MM){
      double a = 0.0;
      for (int l = s8; l < MM; l += 8) a += M[k*67 + l]*srcMid[l];
      a += __shfl_xor(a, 1, 64);
      a += __shfl_xor(a, 2, 64);
      a += __shfl_xor(a, 4, 64);
      if (s8 == 0) temp[k] = a;
    }
  }
  __syncthreads();
  const int s = tid & 3;
  auto dorow = [&](int rr){
    if (rr >= p0 && rr < p0 + MM){
      if (s == 0){
        double val = temp[rr - p0];
        if (dstD) dstD[(size_t)rr*NSP + c] = val;
        else      dstF[perm258(rr)*NSP + perm258(c)] = (float)val;
      }
      return;
    }
    double acc = 0.0;
    for (int k = s; k < MM; k += 4) acc += src[(size_t)rr*NSP + p0 + k]*temp[k];
    acc += __shfl_xor(acc, 1, 64);
    acc += __shfl_xor(acc, 2, 64);
    if (s == 0){
      double f = cpiv ? 0.0 : src[(size_t)rr*NSP + c];
      double val = f - acc;
      if (dstD) dstD[(size_t)rr*NSP + c] = val;
      else      dstF[perm258(rr)*NSP + perm258(c)] = (float)val;
    }
  };
  { int r = tid >> 2; if (r < 256) dorow(r); }
  if (tid < 8) dorow(256 + (tid >> 2));
}

// =================== K2: persistent single-WG ADMM + softmax ===================
// R6/R9 structure with S4a merged per-thread into S4b (B4 removed -> 4 barriers/iter).
// Fold association identical to verified R7 S_X => bit-identical output.
__global__ __launch_bounds__(BLK) __attribute__((amdgpu_waves_per_eu(4, 4)))
void k_admm(const float* __restrict__ N32,
            const float* __restrict__ p32,
            const float* __restrict__ w32,
            float* __restrict__ out){
  __shared__ float2 tb[64][66];       // x^T staging for epilogue only
  __shared__ float2 csTP[64][18];     // col-sum partials (t, p*t) per (b, wave)
  __shared__ float  csX[64][20];      // col-sum partials of x per (b, wave)
  __shared__ __align__(16) float s1f[264];
  __shared__ float s1g2[2];           // [0]=tot(pt), [1]=tot(t)
  __shared__ float s2g[2];            // [0]=a_pg (row 256), [1]=a_g (row 257)
  __shared__ __align__(16) float s2p[4][264];   // matvec partials (fp32)

  const int tid  = threadIdx.x;
  const int lane = tid & 63;          // b
  const int wvid = tid >> 6;          // wave -> rows a = 4*wvid..+3
  const int g    = tid >> 8;          // matvec jj-group (uniform per wave)
  const int c    = tid & 255;         // matvec column

  // ---- register cache of N column c (float4, fully static indexing) ----
  float4 nc4[16];
#pragma unroll
  for (int k2 = 0; k2 < 16; ++k2){
    nc4[k2].x = N32[(64*g + 4*k2 + 0)*NSP + c];
    nc4[k2].y = N32[(64*g + 4*k2 + 1)*NSP + c];
    nc4[k2].z = N32[(64*g + 4*k2 + 2)*NSP + c];
    nc4[k2].w = N32[(64*g + 4*k2 + 3)*NSP + c];
  }
  const float ncg0 = N32[256*NSP + c];
  const float ncg1 = N32[257*NSP + c];

  // tot-row cache for waves 4/5
  float nr0 = 0.f, nr1 = 0.f, nr2 = 0.f, nr3 = 0.f, nrt0 = 0.f, nrt1 = 0.f;
  if (wvid == 4 || wvid == 5){
    int r = 252 + wvid;   // 256 or 257
    nr0 = N32[r*NSP + lane];       nr1 = N32[r*NSP + lane + 64];
    nr2 = N32[r*NSP + lane + 128]; nr3 = N32[r*NSP + lane + 192];
    nrt0 = N32[r*NSP + 256];       nrt1 = N32[r*NSP + 257];
  }

  // ---- state: fp32, f64 dual integrators ----
  float pr[4], wr[4], xr[4], vr[4], tq[4];
  double y2a[4], y2b = 0.0;
#pragma unroll
  for (int q = 0; q < 4; ++q){
    int j = (wvid*4 + q)*64 + lane;
    pr[q] = p32[j]; wr[q] = w32[j];
    xr[q] = 0.f; vr[q] = 0.f; tq[q] = 0.f; y2a[q] = 0.0;
  }
  __syncthreads();

  for (int it = 0; it < NITER; ++it){
    // ========== S1: y2b fold (4xb128), t = w*rhs, in-register row sums ==========
    if (it){
      float ybs = 0.f;
#pragma unroll
      for (int s = 0; s < 4; ++s){
        float4 v4 = *(const float4*)&csX[lane][4*s];
        ybs += (v4.x + v4.y) + (v4.z + v4.w);
      }
      y2b += RHO_ * ((double)ybs - 1.0);
    }
    float base = (float)(2.0*RHO_ - y2b);
    float clt = 0.f, clp = 0.f;
    float st0, st1, st2, st3, sp0, sp1, sp2, sp3;
#pragma unroll
    for (int q = 0; q < 4; ++q){
      float ya = (float)y2a[q];
      float rhs = 1e-3f*xr[q] + pr[q] + 100.f*fabsf(vr[q]) + base - ya;
      float t = wr[q]*rhs;
      float pt = pr[q]*t;
      tq[q] = t;
      clt += t; clp += pt;
      float st = wsum64u(t);
      float sp = wsum64u(pt);
      if (q == 0){ st0 = st; sp0 = sp; }
      else if (q == 1){ st1 = st; sp1 = sp; }
      else if (q == 2){ st2 = st; sp2 = sp; }
      else { st3 = st; sp3 = sp; }
    }
    csTP[lane][(wvid + lane) & 15] = make_float2(clt, clp);
    {
      int l2 = lane & 3;
      float sv_ = (l2 == 0) ? st0 : (l2 == 1) ? st1 : (l2 == 2) ? st2 : st3;
      float pv_ = (l2 == 0) ? sp0 : (l2 == 1) ? sp1 : (l2 == 2) ? sp2 : sp3;
      if (lane < 4)      s1f[192 + wvid*4 + l2] = sv_;   // rs(t)
      else if (lane < 8) s1f[64  + wvid*4 + l2] = pv_;   // rs(pt)
    }
    __syncthreads();  // B1

    // ========== S2: wave-0 column fold + totals ==========
    if (wvid == 0){
      float ct = 0.f, cp = 0.f;
#pragma unroll
      for (int s = 0; s < 8; ++s){
        float4 v4 = *(const float4*)&csTP[lane][2*s];
        ct += v4.x + v4.z; cp += v4.y + v4.w;
      }
      s1f[128 + lane] = ct; s1f[lane] = cp;
      float tt = wsum64u(ct);
      float tp = wsum64u(cp);
      if (lane == 0){ s1g2[1] = tt; s1g2[0] = tp; }
    }
    __syncthreads();  // B2

    // ========== S3: matvec s2p[g][c] (readlane broadcast) ==========
    {
      float sv = s1f[64*g + lane];
      float a0 = 0.f, a1 = 0.f, a2 = 0.f, a3 = 0.f;
#pragma unroll
      for (int k2 = 0; k2 < 16; ++k2){
        float4 nq = nc4[k2];
        a0 += nq.x * __uint_as_float(__builtin_amdgcn_readlane(__float_as_uint(sv), 4*k2 + 0));
        a1 += nq.y * __uint_as_float(__builtin_amdgcn_readlane(__float_as_uint(sv), 4*k2 + 1));
        a2 += nq.z * __uint_as_float(__builtin_amdgcn_readlane(__float_as_uint(sv), 4*k2 + 2));
        a3 += nq.w * __uint_as_float(__builtin_amdgcn_readlane(__float_as_uint(sv), 4*k2 + 3));
      }
      float acc = (a0 + a1) + (a2 + a3);
      if (g == 0) acc += ncg0*s1g2[0] + ncg1*s1g2[1];
      s2p[g][c] = acc;
      if (wvid == 4 || wvid == 5){
        float a32 = nr0*s1f[lane] + nr1*s1f[lane+64]
                  + nr2*s1f[lane+128] + nr3*s1f[lane+192];
        a32 = wsum64u(a32);
        if (lane == 0) s2g[wvid - 4] = a32 + nrt0*s1g2[0] + nrt1*s1g2[1];
      }
    }
    __syncthreads();  // B3

    // ========== S4: per-thread pair folds + x update (B4 removed) ==========
    {
      float sbE  = (s2p[0][128+lane] + s2p[1][128+lane]) + (s2p[2][128+lane] + s2p[3][128+lane]);
      float sbPE = (s2p[0][lane] + s2p[1][lane]) + (s2p[2][lane] + s2p[3][lane]);
      float g1 = s2g[1], g0 = s2g[0];
      float clx = 0.f;
#pragma unroll
      for (int q = 0; q < 4; ++q){
        int arow = wvid*4 + q;
        float sF  = (s2p[0][192+arow] + s2p[1][192+arow]) + (s2p[2][192+arow] + s2p[3][192+arow]);
        float sPF = (s2p[0][64+arow] + s2p[1][64+arow]) + (s2p[2][64+arow] + s2p[3][64+arow]);
        float corr = (g1 + sF) + sbE + pr[q]*((g0 + sPF) + sbPE);
        float xn = tq[q] - wr[q]*corr;
        vr[q] = xn + fminf(vr[q], 0.f);
        xr[q] = xn;
        float rsx = wsum64u(xn);
        y2a[q] += RHO_*((double)rsx - 1.0);
        clx += xn;
        if (it == NITER-1) ((float*)tb)[lane*68 + arow] = xn;   // x^T for epilogue
      }
      csX[lane][wvid] = clx;
    }
    __syncthreads();  // B4'
  }

  // ========== epilogue: clip + softmax(ALPHA*s, axis=-1) ==========
  const float* xb = (const float*)tb;
#pragma unroll
  for (int q = 0; q < 4; ++q){
    int i = wvid*4 + q;                 // n1 row index
    float val = xb[i*68 + lane];        // x[a=lane][b=i]
    val = fminf(fmaxf(val, 0.f), 1.f);
    float mx = wmax64f(val);
    float e = expf(200.f*(val - mx));
    float sm = wsum64f(e);
    out[i*64 + lane] = e / sm;
  }
}

extern "C" void kernel_launch(void* const* d_in, const int* in_sizes, int n_in,
                              void* d_out, int out_size, void* d_ws, size_t ws_size,
                              hipStream_t stream){
  (void)in_sizes; (void)n_in; (void)out_size; (void)ws_size;
  const float* ft  = (const float*)d_in[0];
  const float* fd  = (const float*)d_in[1];
  const float* iou = (const float*)d_in[2];
  const float* Wm  = (const float*)d_in[3];
  const float* bb  = (const float*)d_in[4];
  char* ws = (char*)d_ws;

  double* KsA  = (double*)(ws + OFF_KSA);
  double* KsB  = (double*)(ws + OFF_KSB);
  double* invG = (double*)(ws + OFF_INV);
  float*  N32  = (float*) (ws + OFF_N32);

  hipLaunchKernelGGL(kp_feat, dim3(NWG), dim3(BLK), 0, stream, ft, fd, iou, Wm, bb, ws);
  hipLaunchKernelGGL(kp_pw,   dim3(NWG), dim3(BLK), 0, stream, ws);
  hipLaunchKernelGGL(kp_sums, dim3(1),   dim3(BLK), 0, stream, ws);
  hipLaunchKernelGGL(kp_p3,   dim3(NS),  dim3(BLK), 0, stream, ws);

  hipLaunchKernelGGL(kp_inv<66>,   dim3(1),  dim3(BLK), 0, stream, KsB, 64, invG);
  hipLaunchKernelGGL(kp_apply<66>, dim3(NS), dim3(BLK), 0, stream, KsB, KsA, (float*)nullptr, 64, invG);
  hipLaunchKernelGGL(kp_inv<64>,   dim3(1),  dim3(BLK), 0, stream, KsA, 130, invG);
  hipLaunchKernelGGL(kp_apply<64>, dim3(NS), dim3(BLK), 0, stream, KsA, KsB, (float*)nullptr, 130, invG);
  hipLaunchKernelGGL(kp_inv<64>,   dim3(1),  dim3(BLK), 0, stream, KsB, 194, invG);
  hipLaunchKernelGGL(kp_apply<64>, dim3(NS), dim3(BLK), 0, stream, KsB, (double*)nullptr, N32, 194, invG);

  const float* p32 = (const float*)(ws + OFF_P32);
  const float* w32 = (const float*)(ws + OFF_W32);
  hipLaunchKernelGGL(k_admm, dim3(1), dim3(BLK), 0, stream, N32, p32, w32, (float*)d_out);
}

// Round 12
// 679.029 us; speedup vs baseline: 1.0399x; 1.0399x over previous
//
#include <hip/hip_runtime.h>
#include <math.h>

#define DD 512
#define NS 258
#define NSP 264
#define NWG 64
#define BLK 1024
#define RHO_ 100.0
#define SIG_ 1e-3
#define NITER 150
#define DELTA0 (3969.0 + SIG_ + RHO_)

typedef float v2f __attribute__((ext_vector_type(2)));

// ---------------- workspace byte offsets ----------------
#define OFF_E1     512u        // double[64*512]
#define OFF_SUMS   512u        // double[456] (alias e1; written after e1 dead)
#define OFF_INV    4608u       // double[66*67] (alias e1)
#define OFF_E2     262656u     // double[64*512]
#define OFF_P      524800u     // double[4096]
#define OFF_W      557568u     // double[4096]
#define OFF_P32    590336u     // float[4096]
#define OFF_W32    606720u     // float[4096]
#define OFF_KSA    623104u     // double[258*264]
#define OFF_KSB    1168000u    // double[258*264]
#define OFF_N32    1712896u    // float[258*264] permuted admm ordering

// permutation: GJ ordering [E',F',g'(128),g(129),E(130..193),F(194..257)]
//          ->  admm ordering [E'(0..63),F'(64..127),E(128..191),F(192..255),g'(256),g(257)]
__device__ __forceinline__ int perm258(int i){
  return (i < 128) ? i : (i == 128) ? 256 : (i == 129) ? 257 : (i - 2);
}

// ---------------- DPP reduction helpers (fp32, VALU pipe) ----------------
template<int CTRL>
__device__ __forceinline__ float dppadd(float v){
  int t = __builtin_amdgcn_mov_dpp(__float_as_int(v), CTRL, 0xF, 0xF, 1);
  return v + __int_as_float(t);
}
template<int CTRL>
__device__ __forceinline__ float dppmax(float v){
  int t = __builtin_amdgcn_mov_dpp(__float_as_int(v), CTRL, 0xF, 0xF, 1);
  return fmaxf(v, __int_as_float(t));
}
__device__ __forceinline__ float sum16(float v){
  v = dppadd<0xB1>(v);   // quad_perm xor1
  v = dppadd<0x4E>(v);   // quad_perm xor2
  v = dppadd<0x124>(v);  // row_ror:4
  v = dppadd<0x128>(v);  // row_ror:8
  return v;
}
__device__ __forceinline__ float wsum64f(float v){
  v = sum16(v);
  v += __shfl_xor(v, 16, 64);
  v += __shfl_xor(v, 32, 64);
  return v;
}
// all-VALU wave reduction -> uniform scalar
__device__ __forceinline__ float wsum64u(float v){
  v = sum16(v);
  v = dppadd<0x142>(v);  // row_bcast15
  v = dppadd<0x143>(v);  // row_bcast31
  return __uint_as_float(__builtin_amdgcn_readlane(__float_as_uint(v), 63));
}
__device__ __forceinline__ float wmax64f(float v){
  v = dppmax<0xB1>(v); v = dppmax<0x4E>(v); v = dppmax<0x124>(v); v = dppmax<0x128>(v);
  v = fmaxf(v, __shfl_xor(v, 16, 64));
  v = fmaxf(v, __shfl_xor(v, 32, 64));
  return v;
}

// ---------------- f64 shuffle reductions ----------------
__device__ __forceinline__ double gsum16d(double v){
  v += __shfl_xor(v, 1, 64);
  v += __shfl_xor(v, 2, 64);
  v += __shfl_xor(v, 4, 64);
  v += __shfl_xor(v, 8, 64);
  return v;
}
__device__ __forceinline__ double wsum64d(double v){
  v = gsum16d(v);
  v += __shfl_xor(v, 16, 64);
  v += __shfl_xor(v, 32, 64);
  return v;
}

// ---- Ksmall index decode: order [E'(0..63), F'(64..127), g'(128), g(129), E(130..193), F(194..257)]
__device__ __forceinline__ void decode_idx(int t, int& cls, int& pr, int& ix){
  if (t < 64)       { cls = 1; pr = 1; ix = t; }
  else if (t < 128) { cls = 2; pr = 1; ix = t - 64; }
  else if (t == 128){ cls = 0; pr = 1; ix = 0; }
  else if (t == 129){ cls = 0; pr = 0; ix = 0; }
  else if (t < 194) { cls = 1; pr = 0; ix = t - 130; }
  else              { cls = 2; pr = 0; ix = t - 194; }
}

// ---- closed-form K_small(r,c) ----
__device__ __forceinline__ double ksval(int r, int c, const double* __restrict__ p,
                                        const double* __restrict__ w, const double* sumsL){
  int cr, prr, ir, cc, prc, ic;
  decode_idx(r, cr, prr, ir);
  decode_idx(c, cc, prc, ic);
  int m = prr + prc;
  double tval;
  if (cr == 0 && cc == 0)      tval = sumsL[m];
  else if (cr == 0 && cc == 1) tval = sumsL[8 + m*64 + ic];
  else if (cr == 1 && cc == 0) tval = sumsL[8 + m*64 + ir];
  else if (cr == 0 && cc == 2) tval = sumsL[200 + m*64 + ic];
  else if (cr == 2 && cc == 0) tval = sumsL[200 + m*64 + ir];
  else if (cr == 1 && cc == 1) tval = (ir == ic) ? sumsL[8 + m*64 + ir] : 0.0;
  else if (cr == 2 && cc == 2) tval = (ir == ic) ? sumsL[200 + m*64 + ir] : 0.0;
  else if (cr == 1 && cc == 2){
    double wv = w[ic*64 + ir], pv = p[ic*64 + ir];
    tval = (m == 0) ? wv : (m == 1) ? wv*pv : wv*pv*pv;
  } else {
    double wv = w[ir*64 + ic], pv = p[ir*64 + ic];
    tval = (m == 0) ? wv : (m == 1) ? wv*pv : wv*pv*pv;
  }
  double mv2 = 0.0;
  if (cr == 0 && cc == 0 && prr != prc) mv2 = -2.0;
  if (cr != 0 && cr == cc && ir == ic){
    if (prr != prc) mv2 = 2.0;
    else if (prr == 1) mv2 = -4.0 * RHO_;
  }
  return tval + mv2;
}

// =================== KP1: features (coalesced W-matvec) ===================
__global__ __launch_bounds__(BLK) void kp_feat(const float* __restrict__ ft,
                                               const float* __restrict__ fd,
                                               const float* __restrict__ iou,
                                               const float* __restrict__ Wm,
                                               const float* __restrict__ bb,
                                               char* ws){
  double* e1 = (double*)(ws + OFF_E1);
  double* e2 = (double*)(ws + OFF_E2);
  __shared__ double SH[2216];   // 17.7 KB
  const int tid  = threadIdx.x;
  const int wg   = blockIdx.x;
  const int lane = tid & 63;
  const int wv   = tid >> 6;
  float* ftR = (float*)SH;          // 512 f
  float* fdR = ftR + 512;           // 512 f
  float* u1R = fdR + 512;           // 512 f
  float* u2R = u1R + 512;           // 512 f
  double* m0r = SH + 1024;          // 64
  double* m0c = m0r + 64;           // 64
  double* wp  = m0c + 64;           // 32
  double* sca = wp + 32;            // 8
  double* vbuf = SH + 1192;         // 1024
  const int i = wg;
  if (tid < 512){ ftR[tid] = ft[i*DD + tid]; fdR[tid] = fd[i*DD + tid]; }
  {
    double nf = 0.0, nd = 0.0;
    if (tid < 512){
      float a = ftR[tid], b = fdR[tid];
      nf = (double)a*a; nd = (double)b*b;
    }
    nf = wsum64d(nf); nd = wsum64d(nd);
    if (lane == 0){ wp[wv] = nf; wp[16 + wv] = nd; }
    __syncthreads();
    if (tid == 0){
      double s0 = 0, s1 = 0;
      for (int q = 0; q < 16; ++q){ s0 += wp[q]; s1 += wp[16+q]; }
      sca[0] = s0; sca[1] = s1;
    }
  }
  {
    int j = tid >> 4, sub = tid & 15;
    double ar = 0.0, ac = 0.0;
    for (int t2 = 0; t2 < 32; ++t2){
      int k = t2*16 + sub;
      ar += (double)ftR[k] * (double)fd[(size_t)j*DD + k];
      ac += (double)fdR[k] * (double)ft[(size_t)j*DD + k];
    }
    ar = gsum16d(ar); ac = gsum16d(ac);
    if (sub == 0){
      m0r[j] = ar + (double)iou[i*64 + j];
      m0c[j] = ac + (double)iou[j*64 + i];
    }
  }
  __syncthreads();
  {
    int c = tid & 511, half = tid >> 9;
    const double* m0 = half ? m0c : m0r;
    const float*  FB = half ? ft  : fd;
    double a0 = 0, b0 = 0, c0 = 0, d0 = 0;
    for (int a2 = 0; a2 < 64; a2 += 4){
      a0 += m0[a2]   * (double)FB[(size_t)(a2  )*DD + c];
      b0 += m0[a2+1] * (double)FB[(size_t)(a2+1)*DD + c];
      c0 += m0[a2+2] * (double)FB[(size_t)(a2+2)*DD + c];
      d0 += m0[a2+3] * (double)FB[(size_t)(a2+3)*DD + c];
    }
    double mv = (a0 + b0) + (c0 + d0);
    double nn = wsum64d(mv*mv);
    if (lane == 0) wp[wv] = nn;
    __syncthreads();
    if (tid < 2){
      double s = 0;
      for (int q = tid*8; q < tid*8 + 8; ++q) s += wp[q];
      sca[2 + tid] = sqrt(sca[tid] / s);
    }
    __syncthreads();
    double l = sca[2 + half];
    float* uR = half ? u2R : u1R;
    const float* fR = half ? fdR : ftR;
    uR[c] = (float)((double)fR[c] + l*mv);
  }
  __syncthreads();
  // e = l2norm(relu(u @ W.T + b)) — 16-lane group per output row (coalesced W)
  {
    const int g16 = tid >> 4;          // group -> output row
    const int sub = tid & 15;
    for (int pass = 0; pass < 16; ++pass){
      int c_all = pass*64 + g16;       // 0..1023
      int c = c_all & 511, half = c_all >> 9;
      const float* uR  = half ? u2R : u1R;
      const float* wrp = Wm + (size_t)c*DD;
      double acc = 0.0;
#pragma unroll
      for (int j = 0; j < 8; ++j){
        int k = sub*4 + j*64;
        float4 wq = *(const float4*)(wrp + k);
        float4 uq = *(const float4*)(uR + k);
        acc += (double)uq.x*wq.x + (double)uq.y*wq.y + (double)uq.z*wq.z + (double)uq.w*wq.w;
      }
      acc = gsum16d(acc);
      if (sub == 0) vbuf[c_all] = fmax(acc + (double)bb[c], 0.0);
    }
    __syncthreads();
    double v = vbuf[tid];
    double nn = wsum64d(v*v);
    if (lane == 0) wp[wv] = nn;
    __syncthreads();
    if (tid < 2){
      double s = 0;
      for (int q = tid*8; q < tid*8 + 8; ++q) s += wp[q];
      sca[4 + tid] = 1.0 / fmax(sqrt(s), 1e-12);
    }
    __syncthreads();
    int c = tid & 511, half = tid >> 9;
    double* e = half ? e2 : e1;
    e[(size_t)i*DD + c] = v * sca[4 + half];
  }
}

// =================== KP2: p/w ===================
__global__ __launch_bounds__(BLK) void kp_pw(char* ws){
  const double* e1 = (const double*)(ws + OFF_E1);
  const double* e2 = (const double*)(ws + OFF_E2);
  double* p   = (double*)(ws + OFF_P);
  double* w   = (double*)(ws + OFF_W);
  float*  p32 = (float*) (ws + OFF_P32);
  float*  w32 = (float*) (ws + OFF_W32);
  __shared__ double e2R[512];
  const int tid = threadIdx.x;
  const int a = blockIdx.x;
  if (tid < 512) e2R[tid] = e2[(size_t)a*DD + tid];
  __syncthreads();
  int b = tid >> 4, sub = tid & 15;
  double a0 = 0.0, a1 = 0.0;
  for (int t2 = 0; t2 < 32; t2 += 2){
    a0 += e1[(size_t)b*DD + t2*16 + sub]     * e2R[t2*16 + sub];
    a1 += e1[(size_t)b*DD + (t2+1)*16 + sub] * e2R[(t2+1)*16 + sub];
  }
  double acc = gsum16d(a0 + a1);
  if (sub == 0){
    double pv = acc;
    double wv2 = 1.0 / (DELTA0 - pv);
    int jj = a*64 + b;
    p[jj] = pv; w[jj] = wv2; p32[jj] = (float)pv; w32[jj] = (float)wv2;
  }
}

// =================== KP3: sums + invd -> global ===================
__global__ __launch_bounds__(BLK) void kp_sums(char* ws){
  const double* p = (const double*)(ws + OFF_P);
  const double* w = (const double*)(ws + OFF_W);
  double* sumsG = (double*)(ws + OFF_SUMS);
  __shared__ double sumsL[456];
  const int tid = threadIdx.x;
  int a = tid >> 4, sub = tid & 15;
  {
    double r0 = 0, r1 = 0, r2 = 0;
    for (int b = sub*4; b < sub*4 + 4; ++b){
      double wv = w[a*64 + b], pv = p[a*64 + b];
      r0 += wv; r1 += wv*pv; r2 += wv*pv*pv;
    }
    r0 = gsum16d(r0); r1 = gsum16d(r1); r2 = gsum16d(r2);
    if (sub == 0){ sumsL[200 + a] = r0; sumsL[264 + a] = r1; sumsL[328 + a] = r2; }
  }
  {
    int b2 = tid >> 4;
    double c0 = 0, c1 = 0, c2 = 0;
    for (int a2 = sub*4; a2 < sub*4 + 4; ++a2){
      double wv = w[a2*64 + b2], pv = p[a2*64 + b2];
      c0 += wv; c1 += wv*pv; c2 += wv*pv*pv;
    }
    c0 = gsum16d(c0); c1 = gsum16d(c1); c2 = gsum16d(c2);
    if (sub == 0){ sumsL[8 + b2] = c0; sumsL[72 + b2] = c1; sumsL[136 + b2] = c2; }
  }
  __syncthreads();
  if (tid == 0){
    double t0 = 0, t1 = 0, t2 = 0;
    for (int a3 = 0; a3 < 64; ++a3){
      t0 += sumsL[200 + a3]; t1 += sumsL[264 + a3]; t2 += sumsL[328 + a3];
    }
    sumsL[0] = t0; sumsL[1] = t1; sumsL[2] = t2;
    sumsL[3] = 0; sumsL[4] = 0; sumsL[5] = 0; sumsL[6] = 0; sumsL[7] = 0;
  }
  if (tid >= 64 && tid < 128){
    int k = tid - 64;
    sumsL[392 + k] = 1.0 / (sumsL[136 + k] - 4.0*RHO_);   // E' diag closed form
  }
  __syncthreads();
  for (int idx = tid; idx < 456; idx += BLK) sumsG[idx] = sumsL[idx];
}

// =================== KP4: specialized fused pivot-1 -> KsB (258 WGs, 4-way row split) ===================
__global__ __launch_bounds__(BLK) void kp_p3(char* ws){
  const double* p = (const double*)(ws + OFF_P);
  const double* w = (const double*)(ws + OFF_W);
  const double* sumsG = (const double*)(ws + OFF_SUMS);
  double* KsB = (double*)(ws + OFF_KSB);
  __shared__ double sumsL[456];
  __shared__ double temp[68];
  const int tid = threadIdx.x;
  const int c = blockIdx.x;
  for (int idx = tid; idx < 456; idx += BLK) sumsL[idx] = sumsG[idx];
  __syncthreads();
  const double* invd = sumsL + 392;
  if (tid < 64){
    int k = tid;
    temp[k] = (c < 64) ? ((k == c) ? invd[k] : 0.0) : ksval(k, c, p, w, sumsL) * invd[k];
  }
  __syncthreads();
  const double* tp = temp;
  const int s = tid & 3;
  auto dorow = [&](int rr){
    if (rr < 64){
      if (s == 0) KsB[(size_t)rr*NSP + c] = tp[rr];
      return;
    }
    double acc = 0.0;
    if (rr < 128){
      const double* wr_ = w + (rr-64)*64;
      const double* pr_ = p + (rr-64)*64;
      for (int k = s; k < 64; k += 4){ double pv = pr_[k]; acc += wr_[k]*pv*pv*tp[k]; }
    } else if (rr == 128){
      for (int k = s; k < 64; k += 4) acc += sumsL[136 + k]*tp[k];
    } else if (rr == 129){
      for (int k = s; k < 64; k += 4) acc += sumsL[72 + k]*tp[k];
    } else if (rr < 194){
      if (s == 0){ int ir = rr - 130; acc = (sumsL[72 + ir] + 2.0)*tp[ir]; }
    } else {
      int ir = rr - 194;
      const double* wr_ = w + ir*64;
      const double* pr_ = p + ir*64;
      for (int k = s; k < 64; k += 4) acc += wr_[k]*pr_[k]*tp[k];
    }
    acc += __shfl_xor(acc, 1, 64);
    acc += __shfl_xor(acc, 2, 64);
    if (s == 0){
      double first = (c < 64) ? 0.0 : ksval(rr, c, p, w, sumsL);
      KsB[(size_t)rr*NSP + c] = first - acc;
    }
  };
  { int r = tid >> 2; if (r < 256) dorow(r); }
  if (tid < 8) dorow(256 + (tid >> 2));
}

// =================== KP-inv: rank-4 blocked GJ, branch-free (verified R11) ===================
template<int MM>
__global__ __launch_bounds__(BLK) void kp_inv(const double* __restrict__ src, int p0,
                                              double* __restrict__ invG){
  __shared__ double M[MM*67];
  __shared__ double RV1[MM], RV2[MM], RV3[MM], RV4[MM];
  __shared__ double CV1[MM], CV2[MM], CV3[MM], CV4[MM];
  const int tid = threadIdx.x;
  const int lane = tid & 63, wv = tid >> 6;
  for (int idx = tid; idx < MM*MM; idx += BLK)
    M[(idx/MM)*67 + (idx%MM)] = src[(size_t)(p0 + idx/MM)*NSP + p0 + idx%MM];
  __syncthreads();
  constexpr int K4 = (MM/4)*4;
  for (int k = 0; k < K4; k += 4){
    // ---- stage A: pivots (k,k+1) ----
    if (tid < MM){
      int j = tid;
      double pk  = 1.0 / M[k*67 + k];
      double ck1 = M[(k+1)*67 + k];
      double rv  = M[k*67 + j] * pk;
      if (j == k) rv += pk;
      double rk1 = M[k*67 + k+1] * pk;
      double q   = 1.0 / (M[(k+1)*67 + k+1] - ck1*rk1);
      double r2  = (M[(k+1)*67 + j] - ck1*rv) * q;
      if (j == k+1) r2 += q;
      RV1[j] = rv; RV2[j] = r2;
    } else if (tid >= 512 && tid < 512 + MM){
      int i = tid - 512;
      double pk  = 1.0 / M[k*67 + k];
      double rk1 = M[k*67 + k+1] * pk;
      double cv  = M[i*67 + k];
      if (i == k) cv -= 1.0;
      double c2  = M[i*67 + k+1] - cv*rk1;
      if (i == k+1) c2 -= 1.0;
      CV1[i] = cv; CV2[i] = c2;
    }
    __syncthreads();
    // ---- stage B: pivots (a,b) = (k+2,k+3) on M2 (on the fly) ----
    {
      const int a = k+2, b = k+3;
      if (tid < MM){
        int j = tid;
        double cv1a = CV1[a], cv2a = CV2[a], cv1b = CV1[b], cv2b = CV2[b];
        double rv1a = RV1[a], rv2a = RV2[a], rv1b = RV1[b], rv2b = RV2[b];
        double pk3 = 1.0 / (M[a*67 + a] - cv1a*rv1a - cv2a*rv2a);
        double ck3 = M[b*67 + a] - cv1b*rv1a - cv2b*rv2a;
        double m_aj = M[a*67 + j] - cv1a*RV1[j] - cv2a*RV2[j];
        double rv3 = m_aj * pk3;
        if (j == a) rv3 += pk3;
        double rk3 = (M[a*67 + b] - cv1a*rv1b - cv2a*rv2b) * pk3;
        double Mbb = M[b*67 + b] - cv1b*rv1b - cv2b*rv2b;
        double q3 = 1.0 / (Mbb - ck3*rk3);
        double m_bj = M[b*67 + j] - cv1b*RV1[j] - cv2b*RV2[j];
        double rv4 = (m_bj - ck3*rv3) * q3;
        if (j == b) rv4 += q3;
        RV3[j] = rv3; RV4[j] = rv4;
      } else if (tid >= 512 && tid < 512 + MM){
        int i = tid - 512;
        double cv1a = CV1[a], cv2a = CV2[a];
        double rv1a = RV1[a], rv2a = RV2[a], rv1b = RV1[b], rv2b = RV2[b];
        double pk3 = 1.0 / (M[a*67 + a] - cv1a*rv1a - cv2a*rv2a);
        double rk3 = (M[a*67 + b] - cv1a*rv1b - cv2a*rv2b) * pk3;
        double cv1i = CV1[i], cv2i = CV2[i];
        double cv3 = M[i*67 + a] - cv1i*rv1a - cv2i*rv2a;
        if (i == a) cv3 -= 1.0;
        double m_ib = M[i*67 + b] - cv1i*rv1b - cv2i*rv2b;
        double cv4 = m_ib - cv3*rk3;
        if (i == b) cv4 -= 1.0;
        CV3[i] = cv3; CV4[i] = cv4;
      }
    }
    __syncthreads();
    // ---- fused rank-4 update ----
    {
      double r1l = RV1[lane], r2l = RV2[lane], r3l = RV3[lane], r4l = RV4[lane];
      const bool hi = (lane + 64) < MM;
      double r1h = hi ? RV1[lane+64] : 0.0, r2h = hi ? RV2[lane+64] : 0.0;
      double r3h = hi ? RV3[lane+64] : 0.0, r4h = hi ? RV4[lane+64] : 0.0;
      for (int i = wv; i < MM; i += 16){
        double c1 = CV1[i], c2 = CV2[i], c3 = CV3[i], c4 = CV4[i];
        M[i*67 + lane] -= (c1*r1l + c2*r2l) + (c3*r3l + c4*r4l);
        if (hi) M[i*67 + lane + 64] -= (c1*r1h + c2*r2h) + (c3*r3h + c4*r4h);
      }
    }
    __syncthreads();
  }
  // ---- tail (MM=66): final 2 pivots via rank-2 ----
  if constexpr (K4 < MM){
    const int k = K4;
    if (tid < MM){
      int j = tid;
      double pk  = 1.0 / M[k*67 + k];
      double ck1 = M[(k+1)*67 + k];
      double rv  = M[k*67 + j] * pk;
      if (j == k) rv += pk;
      double rk1 = M[k*67 + k+1] * pk;
      double q   = 1.0 / (M[(k+1)*67 + k+1] - ck1*rk1);
      double r2  = (M[(k+1)*67 + j] - ck1*rv) * q;
      if (j == k+1) r2 += q;
      RV1[j] = rv; RV2[j] = r2;
    } else if (tid >= 512 && tid < 512 + MM){
      int i = tid - 512;
      double pk  = 1.0 / M[k*67 + k];
      double rk1 = M[k*67 + k+1] * pk;
      double cv  = M[i*67 + k];
      if (i == k) cv -= 1.0;
      double c2  = M[i*67 + k+1] - cv*rk1;
      if (i == k+1) c2 -= 1.0;
      CV1[i] = cv; CV2[i] = c2;
    }
    __syncthreads();
    {
      double r1l = RV1[lane], r2l = RV2[lane];
      const bool hi = (lane + 64) < MM;
      double r1h = hi ? RV1[lane+64] : 0.0, r2h = hi ? RV2[lane+64] : 0.0;
      for (int i = wv; i < MM; i += 16){
        double c1 = CV1[i], c2 = CV2[i];
        M[i*67 + lane] -= c1*r1l + c2*r2l;
        if (hi) M[i*67 + lane + 64] -= c1*r1h + c2*r2h;
      }
    }
    __syncthreads();
  }
  for (int idx = tid; idx < MM*MM; idx += BLK)
    invG[(idx/MM)*67 + idx%MM] = M[(idx/MM)*67 + idx%MM];
}

// =================== KP-apply: Schur update (258 WGs, split dots) ===================
template<int MM>
__global__ __launch_bounds__(BLK) void kp_apply(const double* __restrict__ src,
                                                double* __restrict__ dstD,
                                                float* __restrict__ dstF, int p0,
                                                const double* __restrict__ invG){
  __shared__ double M[4422];
  __shared__ double temp[68];
  __shared__ double srcMid[66];
  const int tid = threadIdx.x;
  const int c = blockIdx.x;
  for (int idx = tid; idx < MM*67; idx += BLK) M[idx] = invG[idx];
  if (tid < MM) srcMid[tid] = src[(size_t)(p0 + tid)*NSP + c];
  __syncthreads();
  const bool cpiv = (c >= p0 && c < p0 + MM);
  if (cpiv){
    if (tid < MM) temp[tid] = M[tid*67 + (c - p0)];
  } else {
    int k = tid >> 3, s8 = tid & 7;
    if (k < MM){
      double a = 0.0;
      for (int l = s8; l < MM; l += 8) a += M[k*67 + l]*srcMid[l];
      a += __shfl_xor(a, 1, 64);
      a += __shfl_xor(a, 2, 64);
      a += __shfl_xor(a, 4, 64);
      if (s8 == 0) temp[k] = a;
    }
  }
  __syncthreads();
  const int s = tid & 3;
  auto dorow = [&](int rr){
    if (rr >= p0 && rr < p0 + MM){
      if (s == 0){
        double val = temp[rr - p0];
        if (dstD) dstD[(size_t)rr*NSP + c] = val;
        else      dstF[perm258(rr)*NSP + perm258(c)] = (float)val;
      }
      return;
    }
    double acc = 0.0;
    for (int k = s; k < MM; k += 4) acc += src[(size_t)rr*NSP + p0 + k]*temp[k];
    acc += __shfl_xor(acc, 1, 64);
    acc += __shfl_xor(acc, 2, 64);
    if (s == 0){
      double f = cpiv ? 0.0 : src[(size_t)rr*NSP + c];
      double val = f - acc;
      if (dstD) dstD[(size_t)rr*NSP + c] = val;
      else      dstF[perm258(rr)*NSP + perm258(c)] = (float)val;
    }
  };
  { int r = tid >> 2; if (r < 256) dorow(r); }
  if (tid < 8) dorow(256 + (tid >> 2));
}

// =================== K2: persistent single-WG ADMM + softmax (R9 exact, best: 453 us) ===================
__global__ __launch_bounds__(BLK) __attribute__((amdgpu_waves_per_eu(4, 4)))
void k_admm(const float* __restrict__ N32,
            const float* __restrict__ p32,
            const float* __restrict__ w32,
            float* __restrict__ out){
  __shared__ float2 tb[64][66];       // x^T staging for epilogue only
  __shared__ float2 csTP[64][18];     // col-sum partials (t, p*t) per (b, wave)
  __shared__ float  csX[64][20];      // col-sum partials of x per (b, wave)
  __shared__ __align__(16) float s1f[264];
  __shared__ float s1g2[2];           // [0]=tot(pt), [1]=tot(t)
  __shared__ float s2g[2];            // [0]=a_pg (row 256), [1]=a_g (row 257)
  __shared__ __align__(16) float s2p[4][264];   // matvec partials (fp32)
  __shared__ float2 pairB[64];        // (sbE, sbPE) per b
  __shared__ float2 pairR[64];        // (a_g + sF, a_pg + sPF) per a

  const int tid  = threadIdx.x;
  const int lane = tid & 63;          // b
  const int wvid = tid >> 6;          // wave -> rows a = 4*wvid..+3
  const int g    = tid >> 8;          // matvec jj-group (uniform per wave)
  const int c    = tid & 255;         // matvec column

  // ---- register cache of N column c (float4, fully static indexing) ----
  float4 nc4[16];
#pragma unroll
  for (int k2 = 0; k2 < 16; ++k2){
    nc4[k2].x = N32[(64*g + 4*k2 + 0)*NSP + c];
    nc4[k2].y = N32[(64*g + 4*k2 + 1)*NSP + c];
    nc4[k2].z = N32[(64*g + 4*k2 + 2)*NSP + c];
    nc4[k2].w = N32[(64*g + 4*k2 + 3)*NSP + c];
  }
  const float ncg0 = N32[256*NSP + c];
  const float ncg1 = N32[257*NSP + c];

  // tot-row cache for waves 4/5
  float nr0 = 0.f, nr1 = 0.f, nr2 = 0.f, nr3 = 0.f, nrt0 = 0.f, nrt1 = 0.f;
  if (wvid == 4 || wvid == 5){
    int r = 252 + wvid;   // 256 or 257
    nr0 = N32[r*NSP + lane];       nr1 = N32[r*NSP + lane + 64];
    nr2 = N32[r*NSP + lane + 128]; nr3 = N32[r*NSP + lane + 192];
    nrt0 = N32[r*NSP + 256];       nrt1 = N32[r*NSP + 257];
  }

  // ---- state: fp32, f64 dual integrators ----
  float pr[4], wr[4], xr[4], vr[4], tq[4];
  double y2a[4], y2b = 0.0;
#pragma unroll
  for (int q = 0; q < 4; ++q){
    int j = (wvid*4 + q)*64 + lane;
    pr[q] = p32[j]; wr[q] = w32[j];
    xr[q] = 0.f; vr[q] = 0.f; tq[q] = 0.f; y2a[q] = 0.0;
  }
  __syncthreads();

  for (int it = 0; it < NITER; ++it){
    // ========== S1: y2b fold (4xb128), t = w*rhs, in-register row sums ==========
    if (it){
      float ybs = 0.f;
#pragma unroll
      for (int s = 0; s < 4; ++s){
        float4 v4 = *(const float4*)&csX[lane][4*s];
        ybs += (v4.x + v4.y) + (v4.z + v4.w);
      }
      y2b += RHO_ * ((double)ybs - 1.0);
    }
    float base = (float)(2.0*RHO_ - y2b);
    float clt = 0.f, clp = 0.f;
    float st0, st1, st2, st3, sp0, sp1, sp2, sp3;
#pragma unroll
    for (int q = 0; q < 4; ++q){
      float ya = (float)y2a[q];
      float rhs = 1e-3f*xr[q] + pr[q] + 100.f*fabsf(vr[q]) + base - ya;
      float t = wr[q]*rhs;
      float pt = pr[q]*t;
      tq[q] = t;
      clt += t; clp += pt;
      float st = wsum64u(t);
      float sp = wsum64u(pt);
      if (q == 0){ st0 = st; sp0 = sp; }
      else if (q == 1){ st1 = st; sp1 = sp; }
      else if (q == 2){ st2 = st; sp2 = sp; }
      else { st3 = st; sp3 = sp; }
    }
    csTP[lane][(wvid + lane) & 15] = make_float2(clt, clp);
    {
      int l2 = lane & 3;
      float sv_ = (l2 == 0) ? st0 : (l2 == 1) ? st1 : (l2 == 2) ? st2 : st3;
      float pv_ = (l2 == 0) ? sp0 : (l2 == 1) ? sp1 : (l2 == 2) ? sp2 : sp3;
      if (lane < 4)      s1f[192 + wvid*4 + l2] = sv_;   // rs(t)
      else if (lane < 8) s1f[64  + wvid*4 + l2] = pv_;   // rs(pt)
    }
    __syncthreads();  // B1

    // ========== S2: wave-0 column fold + totals ==========
    if (wvid == 0){
      float ct = 0.f, cp = 0.f;
#pragma unroll
      for (int s = 0; s < 8; ++s){
        float4 v4 = *(const float4*)&csTP[lane][2*s];
        ct += v4.x + v4.z; cp += v4.y + v4.w;
      }
      s1f[128 + lane] = ct; s1f[lane] = cp;
      float tt = wsum64u(ct);
      float tp = wsum64u(cp);
      if (lane == 0){ s1g2[1] = tt; s1g2[0] = tp; }
    }
    __syncthreads();  // B2

    // ========== S3: matvec s2p[g][c] (readlane broadcast) ==========
    {
      float sv = s1f[64*g + lane];
      float a0 = 0.f, a1 = 0.f, a2 = 0.f, a3 = 0.f;
#pragma unroll
      for (int k2 = 0; k2 < 16; ++k2){
        float4 nq = nc4[k2];
        a0 += nq.x * __uint_as_float(__builtin_amdgcn_readlane(__float_as_uint(sv), 4*k2 + 0));
        a1 += nq.y * __uint_as_float(__builtin_amdgcn_readlane(__float_as_uint(sv), 4*k2 + 1));
        a2 += nq.z * __uint_as_float(__builtin_amdgcn_readlane(__float_as_uint(sv), 4*k2 + 2));
        a3 += nq.w * __uint_as_float(__builtin_amdgcn_readlane(__float_as_uint(sv), 4*k2 + 3));
      }
      float acc = (a0 + a1) + (a2 + a3);
      if (g == 0) acc += ncg0*s1g2[0] + ncg1*s1g2[1];
      s2p[g][c] = acc;
      if (wvid == 4 || wvid == 5){
        float a32 = nr0*s1f[lane] + nr1*s1f[lane+64]
                  + nr2*s1f[lane+128] + nr3*s1f[lane+192];
        a32 = wsum64u(a32);
        if (lane == 0) s2g[wvid - 4] = a32 + nrt0*s1g2[0] + nrt1*s1g2[1];
      }
    }
    __syncthreads();  // B3

    // ========== S4a: fold into packed pairs (2 half-waves) ==========
    if (tid < 64){
      int b = tid;
      float sbE  = (s2p[0][128+b] + s2p[1][128+b]) + (s2p[2][128+b] + s2p[3][128+b]);
      float sbPE = (s2p[0][b] + s2p[1][b]) + (s2p[2][b] + s2p[3][b]);
      pairB[b] = make_float2(sbE, sbPE);
    } else if (tid < 128){
      int a = tid - 64;
      float sF  = (s2p[0][192+a] + s2p[1][192+a]) + (s2p[2][192+a] + s2p[3][192+a]);
      float sPF = (s2p[0][64+a] + s2p[1][64+a]) + (s2p[2][64+a] + s2p[3][64+a]);
      pairR[a] = make_float2(s2g[1] + sF, s2g[0] + sPF);
    }
    __syncthreads();  // B4

    // ========== S4b: x update, v update, y2a, x col partials ==========
    {
      float2 pb = pairB[lane];
      float clx = 0.f;
#pragma unroll
      for (int q = 0; q < 4; ++q){
        int arow = wvid*4 + q;
        float2 prw = pairR[arow];
        float corr = prw.x + pb.x + pr[q]*(prw.y + pb.y);
        float xn = tq[q] - wr[q]*corr;
        vr[q] = xn + fminf(vr[q], 0.f);
        xr[q] = xn;
        float rsx = wsum64u(xn);
        y2a[q] += RHO_*((double)rsx - 1.0);
        clx += xn;
        if (it == NITER-1) ((float*)tb)[lane*68 + arow] = xn;   // x^T for epilogue
      }
      csX[lane][wvid] = clx;
    }
    __syncthreads();  // B5
  }

  // ========== epilogue: clip + softmax(ALPHA*s, axis=-1) ==========
  const float* xb = (const float*)tb;
#pragma unroll
  for (int q = 0; q < 4; ++q){
    int i = wvid*4 + q;                 // n1 row index
    float val = xb[i*68 + lane];        // x[a=lane][b=i]
    val = fminf(fmaxf(val, 0.f), 1.f);
    float mx = wmax64f(val);
    float e = expf(200.f*(val - mx));
    float sm = wsum64f(e);
    out[i*64 + lane] = e / sm;
  }
}

extern "C" void kernel_launch(void* const* d_in, const int* in_sizes, int n_in,
                              void* d_out, int out_size, void* d_ws, size_t ws_size,
                              hipStream_t stream){
  (void)in_sizes; (void)n_in; (void)out_size; (void)ws_size;
  const float* ft  = (const float*)d_in[0];
  const float* fd  = (const float*)d_in[1];
  const float* iou = (const float*)d_in[2];
  const float* Wm  = (const float*)d_in[3];
  const float* bb  = (const float*)d_in[4];
  char* ws = (char*)d_ws;

  double* KsA  = (double*)(ws + OFF_KSA);
  double* KsB  = (double*)(ws + OFF_KSB);
  double* invG = (double*)(ws + OFF_INV);
  float*  N32  = (float*) (ws + OFF_N32);

  hipLaunchKernelGGL(kp_feat, dim3(NWG), dim3(BLK), 0, stream, ft, fd, iou, Wm, bb, ws);
  hipLaunchKernelGGL(kp_pw,   dim3(NWG), dim3(BLK), 0, stream, ws);
  hipLaunchKernelGGL(kp_sums, dim3(1),   dim3(BLK), 0, stream, ws);
  hipLaunchKernelGGL(kp_p3,   dim3(NS),  dim3(BLK), 0, stream, ws);

  hipLaunchKernelGGL(kp_inv<66>,   dim3(1),  dim3(BLK), 0, stream, KsB, 64, invG);
  hipLaunchKernelGGL(kp_apply<66>, dim3(NS), dim3(BLK), 0, stream, KsB, KsA, (float*)nullptr, 64, invG);
  hipLaunchKernelGGL(kp_inv<64>,   dim3(1),  dim3(BLK), 0, stream, KsA, 130, invG);
  hipLaunchKernelGGL(kp_apply<64>, dim3(NS), dim3(BLK), 0, stream, KsA, KsB, (float*)nullptr, 130, invG);
  hipLaunchKernelGGL(kp_inv<64>,   dim3(1),  dim3(BLK), 0, stream, KsB, 194, invG);
  hipLaunchKernelGGL(kp_apply<64>, dim3(NS), dim3(BLK), 0, stream, KsB, (double*)nullptr, N32, 194, invG);

  const float* p32 = (const float*)(ws + OFF_P32);
  const float* w32 = (const float*)(ws + OFF_W32);
  hipLaunchKernelGGL(k_admm, dim3(1), dim3(BLK), 0, stream, N32, p32, w32, (float*)d_out);
}

// Round 13
// 656.231 us; speedup vs baseline: 1.0761x; 1.0347x over previous
//
#include <hip/hip_runtime.h>
#include <math.h>

#define DD 512
#define NS 258
#define NSP 264
#define NWG 64
#define BLK 1024
#define RHO_ 100.0
#define SIG_ 1e-3
#define NITER 150
#define DELTA0 (3969.0 + SIG_ + RHO_)

typedef float v2f __attribute__((ext_vector_type(2)));

// ---------------- workspace byte offsets ----------------
#define OFF_E1     512u        // double[64*512]
#define OFF_SUMS   512u        // double[456] (alias e1; written after e1 dead)
#define OFF_INV    4608u       // double[66*67] (alias e1)
#define OFF_E2     262656u     // double[64*512]
#define OFF_P      524800u     // double[4096]
#define OFF_W      557568u     // double[4096]
#define OFF_P32    590336u     // float[4096]
#define OFF_W32    606720u     // float[4096]
#define OFF_KSA    623104u     // double[258*264]
#define OFF_KSB    1168000u    // double[258*264]
#define OFF_N32    1712896u    // float[258*264] permuted admm ordering

// permutation: GJ ordering [E',F',g'(128),g(129),E(130..193),F(194..257)]
//          ->  admm ordering [E'(0..63),F'(64..127),E(128..191),F(192..255),g'(256),g(257)]
__device__ __forceinline__ int perm258(int i){
  return (i < 128) ? i : (i == 128) ? 256 : (i == 129) ? 257 : (i - 2);
}

// ---------------- DPP reduction helpers (fp32, VALU pipe) ----------------
template<int CTRL>
__device__ __forceinline__ float dppadd(float v){
  int t = __builtin_amdgcn_mov_dpp(__float_as_int(v), CTRL, 0xF, 0xF, 1);
  return v + __int_as_float(t);
}
template<int CTRL>
__device__ __forceinline__ float dppmax(float v){
  int t = __builtin_amdgcn_mov_dpp(__float_as_int(v), CTRL, 0xF, 0xF, 1);
  return fmaxf(v, __int_as_float(t));
}
__device__ __forceinline__ float sum16(float v){
  v = dppadd<0xB1>(v);   // quad_perm xor1
  v = dppadd<0x4E>(v);   // quad_perm xor2
  v = dppadd<0x124>(v);  // row_ror:4
  v = dppadd<0x128>(v);  // row_ror:8
  return v;
}
__device__ __forceinline__ float wsum64f(float v){
  v = sum16(v);
  v += __shfl_xor(v, 16, 64);
  v += __shfl_xor(v, 32, 64);
  return v;
}
// all-VALU wave reduction -> uniform scalar
__device__ __forceinline__ float wsum64u(float v){
  v = sum16(v);
  v = dppadd<0x142>(v);  // row_bcast15
  v = dppadd<0x143>(v);  // row_bcast31
  return __uint_as_float(__builtin_amdgcn_readlane(__float_as_uint(v), 63));
}
__device__ __forceinline__ float wmax64f(float v){
  v = dppmax<0xB1>(v); v = dppmax<0x4E>(v); v = dppmax<0x124>(v); v = dppmax<0x128>(v);
  v = fmaxf(v, __shfl_xor(v, 16, 64));
  v = fmaxf(v, __shfl_xor(v, 32, 64));
  return v;
}

// ---------------- f64 shuffle reductions ----------------
__device__ __forceinline__ double gsum16d(double v){
  v += __shfl_xor(v, 1, 64);
  v += __shfl_xor(v, 2, 64);
  v += __shfl_xor(v, 4, 64);
  v += __shfl_xor(v, 8, 64);
  return v;
}
__device__ __forceinline__ double wsum64d(double v){
  v = gsum16d(v);
  v += __shfl_xor(v, 16, 64);
  v += __shfl_xor(v, 32, 64);
  return v;
}

// ---- Ksmall index decode: order [E'(0..63), F'(64..127), g'(128), g(129), E(130..193), F(194..257)]
__device__ __forceinline__ void decode_idx(int t, int& cls, int& pr, int& ix){
  if (t < 64)       { cls = 1; pr = 1; ix = t; }
  else if (t < 128) { cls = 2; pr = 1; ix = t - 64; }
  else if (t == 128){ cls = 0; pr = 1; ix = 0; }
  else if (t == 129){ cls = 0; pr = 0; ix = 0; }
  else if (t < 194) { cls = 1; pr = 0; ix = t - 130; }
  else              { cls = 2; pr = 0; ix = t - 194; }
}

// ---- closed-form K_small(r,c) ----
__device__ __forceinline__ double ksval(int r, int c, const double* __restrict__ p,
                                        const double* __restrict__ w, const double* sumsL){
  int cr, prr, ir, cc, prc, ic;
  decode_idx(r, cr, prr, ir);
  decode_idx(c, cc, prc, ic);
  int m = prr + prc;
  double tval;
  if (cr == 0 && cc == 0)      tval = sumsL[m];
  else if (cr == 0 && cc == 1) tval = sumsL[8 + m*64 + ic];
  else if (cr == 1 && cc == 0) tval = sumsL[8 + m*64 + ir];
  else if (cr == 0 && cc == 2) tval = sumsL[200 + m*64 + ic];
  else if (cr == 2 && cc == 0) tval = sumsL[200 + m*64 + ir];
  else if (cr == 1 && cc == 1) tval = (ir == ic) ? sumsL[8 + m*64 + ir] : 0.0;
  else if (cr == 2 && cc == 2) tval = (ir == ic) ? sumsL[200 + m*64 + ir] : 0.0;
  else if (cr == 1 && cc == 2){
    double wv = w[ic*64 + ir], pv = p[ic*64 + ir];
    tval = (m == 0) ? wv : (m == 1) ? wv*pv : wv*pv*pv;
  } else {
    double wv = w[ir*64 + ic], pv = p[ir*64 + ic];
    tval = (m == 0) ? wv : (m == 1) ? wv*pv : wv*pv*pv;
  }
  double mv2 = 0.0;
  if (cr == 0 && cc == 0 && prr != prc) mv2 = -2.0;
  if (cr != 0 && cr == cc && ir == ic){
    if (prr != prc) mv2 = 2.0;
    else if (prr == 1) mv2 = -4.0 * RHO_;
  }
  return tval + mv2;
}

// =================== KP1: features (coalesced W-matvec) ===================
__global__ __launch_bounds__(BLK) void kp_feat(const float* __restrict__ ft,
                                               const float* __restrict__ fd,
                                               const float* __restrict__ iou,
                                               const float* __restrict__ Wm,
                                               const float* __restrict__ bb,
                                               char* ws){
  double* e1 = (double*)(ws + OFF_E1);
  double* e2 = (double*)(ws + OFF_E2);
  __shared__ double SH[2216];   // 17.7 KB
  const int tid  = threadIdx.x;
  const int wg   = blockIdx.x;
  const int lane = tid & 63;
  const int wv   = tid >> 6;
  float* ftR = (float*)SH;          // 512 f
  float* fdR = ftR + 512;           // 512 f
  float* u1R = fdR + 512;           // 512 f
  float* u2R = u1R + 512;           // 512 f
  double* m0r = SH + 1024;          // 64
  double* m0c = m0r + 64;           // 64
  double* wp  = m0c + 64;           // 32
  double* sca = wp + 32;            // 8
  double* vbuf = SH + 1192;         // 1024
  const int i = wg;
  if (tid < 512){ ftR[tid] = ft[i*DD + tid]; fdR[tid] = fd[i*DD + tid]; }
  {
    double nf = 0.0, nd = 0.0;
    if (tid < 512){
      float a = ftR[tid], b = fdR[tid];
      nf = (double)a*a; nd = (double)b*b;
    }
    nf = wsum64d(nf); nd = wsum64d(nd);
    if (lane == 0){ wp[wv] = nf; wp[16 + wv] = nd; }
    __syncthreads();
    if (tid == 0){
      double s0 = 0, s1 = 0;
      for (int q = 0; q < 16; ++q){ s0 += wp[q]; s1 += wp[16+q]; }
      sca[0] = s0; sca[1] = s1;
    }
  }
  {
    int j = tid >> 4, sub = tid & 15;
    double ar = 0.0, ac = 0.0;
    for (int t2 = 0; t2 < 32; ++t2){
      int k = t2*16 + sub;
      ar += (double)ftR[k] * (double)fd[(size_t)j*DD + k];
      ac += (double)fdR[k] * (double)ft[(size_t)j*DD + k];
    }
    ar = gsum16d(ar); ac = gsum16d(ac);
    if (sub == 0){
      m0r[j] = ar + (double)iou[i*64 + j];
      m0c[j] = ac + (double)iou[j*64 + i];
    }
  }
  __syncthreads();
  {
    int c = tid & 511, half = tid >> 9;
    const double* m0 = half ? m0c : m0r;
    const float*  FB = half ? ft  : fd;
    double a0 = 0, b0 = 0, c0 = 0, d0 = 0;
    for (int a2 = 0; a2 < 64; a2 += 4){
      a0 += m0[a2]   * (double)FB[(size_t)(a2  )*DD + c];
      b0 += m0[a2+1] * (double)FB[(size_t)(a2+1)*DD + c];
      c0 += m0[a2+2] * (double)FB[(size_t)(a2+2)*DD + c];
      d0 += m0[a2+3] * (double)FB[(size_t)(a2+3)*DD + c];
    }
    double mv = (a0 + b0) + (c0 + d0);
    double nn = wsum64d(mv*mv);
    if (lane == 0) wp[wv] = nn;
    __syncthreads();
    if (tid < 2){
      double s = 0;
      for (int q = tid*8; q < tid*8 + 8; ++q) s += wp[q];
      sca[2 + tid] = sqrt(sca[tid] / s);
    }
    __syncthreads();
    double l = sca[2 + half];
    float* uR = half ? u2R : u1R;
    const float* fR = half ? fdR : ftR;
    uR[c] = (float)((double)fR[c] + l*mv);
  }
  __syncthreads();
  // e = l2norm(relu(u @ W.T + b)) — 16-lane group per output row (coalesced W)
  {
    const int g16 = tid >> 4;          // group -> output row
    const int sub = tid & 15;
    for (int pass = 0; pass < 16; ++pass){
      int c_all = pass*64 + g16;       // 0..1023
      int c = c_all & 511, half = c_all >> 9;
      const float* uR  = half ? u2R : u1R;
      const float* wrp = Wm + (size_t)c*DD;
      double acc = 0.0;
#pragma unroll
      for (int j = 0; j < 8; ++j){
        int k = sub*4 + j*64;
        float4 wq = *(const float4*)(wrp + k);
        float4 uq = *(const float4*)(uR + k);
        acc += (double)uq.x*wq.x + (double)uq.y*wq.y + (double)uq.z*wq.z + (double)uq.w*wq.w;
      }
      acc = gsum16d(acc);
      if (sub == 0) vbuf[c_all] = fmax(acc + (double)bb[c], 0.0);
    }
    __syncthreads();
    double v = vbuf[tid];
    double nn = wsum64d(v*v);
    if (lane == 0) wp[wv] = nn;
    __syncthreads();
    if (tid < 2){
      double s = 0;
      for (int q = tid*8; q < tid*8 + 8; ++q) s += wp[q];
      sca[4 + tid] = 1.0 / fmax(sqrt(s), 1e-12);
    }
    __syncthreads();
    int c = tid & 511, half = tid >> 9;
    double* e = half ? e2 : e1;
    e[(size_t)i*DD + c] = v * sca[4 + half];
  }
}

// =================== KP2: p/w ===================
__global__ __launch_bounds__(BLK) void kp_pw(char* ws){
  const double* e1 = (const double*)(ws + OFF_E1);
  const double* e2 = (const double*)(ws + OFF_E2);
  double* p   = (double*)(ws + OFF_P);
  double* w   = (double*)(ws + OFF_W);
  float*  p32 = (float*) (ws + OFF_P32);
  float*  w32 = (float*) (ws + OFF_W32);
  __shared__ double e2R[512];
  const int tid = threadIdx.x;
  const int a = blockIdx.x;
  if (tid < 512) e2R[tid] = e2[(size_t)a*DD + tid];
  __syncthreads();
  int b = tid >> 4, sub = tid & 15;
  double a0 = 0.0, a1 = 0.0;
  for (int t2 = 0; t2 < 32; t2 += 2){
    a0 += e1[(size_t)b*DD + t2*16 + sub]     * e2R[t2*16 + sub];
    a1 += e1[(size_t)b*DD + (t2+1)*16 + sub] * e2R[(t2+1)*16 + sub];
  }
  double acc = gsum16d(a0 + a1);
  if (sub == 0){
    double pv = acc;
    double wv2 = 1.0 / (DELTA0 - pv);
    int jj = a*64 + b;
    p[jj] = pv; w[jj] = wv2; p32[jj] = (float)pv; w32[jj] = (float)wv2;
  }
}

// =================== KP3: sums + invd -> global ===================
__global__ __launch_bounds__(BLK) void kp_sums(char* ws){
  const double* p = (const double*)(ws + OFF_P);
  const double* w = (const double*)(ws + OFF_W);
  double* sumsG = (double*)(ws + OFF_SUMS);
  __shared__ double sumsL[456];
  const int tid = threadIdx.x;
  int a = tid >> 4, sub = tid & 15;
  {
    double r0 = 0, r1 = 0, r2 = 0;
    for (int b = sub*4; b < sub*4 + 4; ++b){
      double wv = w[a*64 + b], pv = p[a*64 + b];
      r0 += wv; r1 += wv*pv; r2 += wv*pv*pv;
    }
    r0 = gsum16d(r0); r1 = gsum16d(r1); r2 = gsum16d(r2);
    if (sub == 0){ sumsL[200 + a] = r0; sumsL[264 + a] = r1; sumsL[328 + a] = r2; }
  }
  {
    int b2 = tid >> 4;
    double c0 = 0, c1 = 0, c2 = 0;
    for (int a2 = sub*4; a2 < sub*4 + 4; ++a2){
      double wv = w[a2*64 + b2], pv = p[a2*64 + b2];
      c0 += wv; c1 += wv*pv; c2 += wv*pv*pv;
    }
    c0 = gsum16d(c0); c1 = gsum16d(c1); c2 = gsum16d(c2);
    if (sub == 0){ sumsL[8 + b2] = c0; sumsL[72 + b2] = c1; sumsL[136 + b2] = c2; }
  }
  __syncthreads();
  if (tid == 0){
    double t0 = 0, t1 = 0, t2 = 0;
    for (int a3 = 0; a3 < 64; ++a3){
      t0 += sumsL[200 + a3]; t1 += sumsL[264 + a3]; t2 += sumsL[328 + a3];
    }
    sumsL[0] = t0; sumsL[1] = t1; sumsL[2] = t2;
    sumsL[3] = 0; sumsL[4] = 0; sumsL[5] = 0; sumsL[6] = 0; sumsL[7] = 0;
  }
  if (tid >= 64 && tid < 128){
    int k = tid - 64;
    sumsL[392 + k] = 1.0 / (sumsL[136 + k] - 4.0*RHO_);   // E' diag closed form
  }
  __syncthreads();
  for (int idx = tid; idx < 456; idx += BLK) sumsG[idx] = sumsL[idx];
}

// =================== KP4: specialized fused pivot-1 -> KsB (258 WGs, 4-way row split) ===================
__global__ __launch_bounds__(BLK) void kp_p3(char* ws){
  const double* p = (const double*)(ws + OFF_P);
  const double* w = (const double*)(ws + OFF_W);
  const double* sumsG = (const double*)(ws + OFF_SUMS);
  double* KsB = (double*)(ws + OFF_KSB);
  __shared__ double sumsL[456];
  __shared__ double temp[68];
  const int tid = threadIdx.x;
  const int c = blockIdx.x;
  for (int idx = tid; idx < 456; idx += BLK) sumsL[idx] = sumsG[idx];
  __syncthreads();
  const double* invd = sumsL + 392;
  if (tid < 64){
    int k = tid;
    temp[k] = (c < 64) ? ((k == c) ? invd[k] : 0.0) : ksval(k, c, p, w, sumsL) * invd[k];
  }
  __syncthreads();
  const double* tp = temp;
  const int s = tid & 3;
  auto dorow = [&](int rr){
    if (rr < 64){
      if (s == 0) KsB[(size_t)rr*NSP + c] = tp[rr];
      return;
    }
    double acc = 0.0;
    if (rr < 128){
      const double* wr_ = w + (rr-64)*64;
      const double* pr_ = p + (rr-64)*64;
      for (int k = s; k < 64; k += 4){ double pv = pr_[k]; acc += wr_[k]*pv*pv*tp[k]; }
    } else if (rr == 128){
      for (int k = s; k < 64; k += 4) acc += sumsL[136 + k]*tp[k];
    } else if (rr == 129){
      for (int k = s; k < 64; k += 4) acc += sumsL[72 + k]*tp[k];
    } else if (rr < 194){
      if (s == 0){ int ir = rr - 130; acc = (sumsL[72 + ir] + 2.0)*tp[ir]; }
    } else {
      int ir = rr - 194;
      const double* wr_ = w + ir*64;
      const double* pr_ = p + ir*64;
      for (int k = s; k < 64; k += 4) acc += wr_[k]*pr_[k]*tp[k];
    }
    acc += __shfl_xor(acc, 1, 64);
    acc += __shfl_xor(acc, 2, 64);
    if (s == 0){
      double first = (c < 64) ? 0.0 : ksval(rr, c, p, w, sumsL);
      KsB[(size_t)rr*NSP + c] = first - acc;
    }
  };
  { int r = tid >> 2; if (r < 256) dorow(r); }
  if (tid < 8) dorow(256 + (tid >> 2));
}

// =================== KP-inv: rank-4 blocked GJ, branch-free (verified R11) ===================
template<int MM>
__global__ __launch_bounds__(BLK) void kp_inv(const double* __restrict__ src, int p0,
                                              double* __restrict__ invG){
  __shared__ double M[MM*67];
  __shared__ double RV1[MM], RV2[MM], RV3[MM], RV4[MM];
  __shared__ double CV1[MM], CV2[MM], CV3[MM], CV4[MM];
  const int tid = threadIdx.x;
  const int lane = tid & 63, wv = tid >> 6;
  for (int idx = tid; idx < MM*MM; idx += BLK)
    M[(idx/MM)*67 + (idx%MM)] = src[(size_t)(p0 + idx/MM)*NSP + p0 + idx%MM];
  __syncthreads();
  constexpr int K4 = (MM/4)*4;
  for (int k = 0; k < K4; k += 4){
    // ---- stage A: pivots (k,k+1) ----
    if (tid < MM){
      int j = tid;
      double pk  = 1.0 / M[k*67 + k];
      double ck1 = M[(k+1)*67 + k];
      double rv  = M[k*67 + j] * pk;
      if (j == k) rv += pk;
      double rk1 = M[k*67 + k+1] * pk;
      double q   = 1.0 / (M[(k+1)*67 + k+1] - ck1*rk1);
      double r2  = (M[(k+1)*67 + j] - ck1*rv) * q;
      if (j == k+1) r2 += q;
      RV1[j] = rv; RV2[j] = r2;
    } else if (tid >= 512 && tid < 512 + MM){
      int i = tid - 512;
      double pk  = 1.0 / M[k*67 + k];
      double rk1 = M[k*67 + k+1] * pk;
      double cv  = M[i*67 + k];
      if (i == k) cv -= 1.0;
      double c2  = M[i*67 + k+1] - cv*rk1;
      if (i == k+1) c2 -= 1.0;
      CV1[i] = cv; CV2[i] = c2;
    }
    __syncthreads();
    // ---- stage B: pivots (a,b) = (k+2,k+3) on M2 (on the fly) ----
    {
      const int a = k+2, b = k+3;
      if (tid < MM){
        int j = tid;
        double cv1a = CV1[a], cv2a = CV2[a], cv1b = CV1[b], cv2b = CV2[b];
        double rv1a = RV1[a], rv2a = RV2[a], rv1b = RV1[b], rv2b = RV2[b];
        double pk3 = 1.0 / (M[a*67 + a] - cv1a*rv1a - cv2a*rv2a);
        double ck3 = M[b*67 + a] - cv1b*rv1a - cv2b*rv2a;
        double m_aj = M[a*67 + j] - cv1a*RV1[j] - cv2a*RV2[j];
        double rv3 = m_aj * pk3;
        if (j == a) rv3 += pk3;
        double rk3 = (M[a*67 + b] - cv1a*rv1b - cv2a*rv2b) * pk3;
        double Mbb = M[b*67 + b] - cv1b*rv1b - cv2b*rv2b;
        double q3 = 1.0 / (Mbb - ck3*rk3);
        double m_bj = M[b*67 + j] - cv1b*RV1[j] - cv2b*RV2[j];
        double rv4 = (m_bj - ck3*rv3) * q3;
        if (j == b) rv4 += q3;
        RV3[j] = rv3; RV4[j] = rv4;
      } else if (tid >= 512 && tid < 512 + MM){
        int i = tid - 512;
        double cv1a = CV1[a], cv2a = CV2[a];
        double rv1a = RV1[a], rv2a = RV2[a], rv1b = RV1[b], rv2b = RV2[b];
        double pk3 = 1.0 / (M[a*67 + a] - cv1a*rv1a - cv2a*rv2a);
        double rk3 = (M[a*67 + b] - cv1a*rv1b - cv2a*rv2b) * pk3;
        double cv1i = CV1[i], cv2i = CV2[i];
        double cv3 = M[i*67 + a] - cv1i*rv1a - cv2i*rv2a;
        if (i == a) cv3 -= 1.0;
        double m_ib = M[i*67 + b] - cv1i*rv1b - cv2i*rv2b;
        double cv4 = m_ib - cv3*rk3;
        if (i == b) cv4 -= 1.0;
        CV3[i] = cv3; CV4[i] = cv4;
      }
    }
    __syncthreads();
    // ---- fused rank-4 update ----
    {
      double r1l = RV1[lane], r2l = RV2[lane], r3l = RV3[lane], r4l = RV4[lane];
      const bool hi = (lane + 64) < MM;
      double r1h = hi ? RV1[lane+64] : 0.0, r2h = hi ? RV2[lane+64] : 0.0;
      double r3h = hi ? RV3[lane+64] : 0.0, r4h = hi ? RV4[lane+64] : 0.0;
      for (int i = wv; i < MM; i += 16){
        double c1 = CV1[i], c2 = CV2[i], c3 = CV3[i], c4 = CV4[i];
        M[i*67 + lane] -= (c1*r1l + c2*r2l) + (c3*r3l + c4*r4l);
        if (hi) M[i*67 + lane + 64] -= (c1*r1h + c2*r2h) + (c3*r3h + c4*r4h);
      }
    }
    __syncthreads();
  }
  // ---- tail (MM=66): final 2 pivots via rank-2 ----
  if constexpr (K4 < MM){
    const int k = K4;
    if (tid < MM){
      int j = tid;
      double pk  = 1.0 / M[k*67 + k];
      double ck1 = M[(k+1)*67 + k];
      double rv  = M[k*67 + j] * pk;
      if (j == k) rv += pk;
      double rk1 = M[k*67 + k+1] * pk;
      double q   = 1.0 / (M[(k+1)*67 + k+1] - ck1*rk1);
      double r2  = (M[(k+1)*67 + j] - ck1*rv) * q;
      if (j == k+1) r2 += q;
      RV1[j] = rv; RV2[j] = r2;
    } else if (tid >= 512 && tid < 512 + MM){
      int i = tid - 512;
      double pk  = 1.0 / M[k*67 + k];
      double rk1 = M[k*67 + k+1] * pk;
      double cv  = M[i*67 + k];
      if (i == k) cv -= 1.0;
      double c2  = M[i*67 + k+1] - cv*rk1;
      if (i == k+1) c2 -= 1.0;
      CV1[i] = cv; CV2[i] = c2;
    }
    __syncthreads();
    {
      double r1l = RV1[lane], r2l = RV2[lane];
      const bool hi = (lane + 64) < MM;
      double r1h = hi ? RV1[lane+64] : 0.0, r2h = hi ? RV2[lane+64] : 0.0;
      for (int i = wv; i < MM; i += 16){
        double c1 = CV1[i], c2 = CV2[i];
        M[i*67 + lane] -= c1*r1l + c2*r2l;
        if (hi) M[i*67 + lane + 64] -= c1*r1h + c2*r2h;
      }
    }
    __syncthreads();
  }
  for (int idx = tid; idx < MM*MM; idx += BLK)
    invG[(idx/MM)*67 + idx%MM] = M[(idx/MM)*67 + idx%MM];
}

// =================== KP-apply: Schur update (258 WGs, split dots) ===================
template<int MM>
__global__ __launch_bounds__(BLK) void kp_apply(const double* __restrict__ src,
                                                double* __restrict__ dstD,
                                                float* __restrict__ dstF, int p0,
                                                const double* __restrict__ invG){
  __shared__ double M[4422];
  __shared__ double temp[68];
  __shared__ double srcMid[66];
  const int tid = threadIdx.x;
  const int c = blockIdx.x;
  for (int idx = tid; idx < MM*67; idx += BLK) M[idx] = invG[idx];
  if (tid < MM) srcMid[tid] = src[(size_t)(p0 + tid)*NSP + c];
  __syncthreads();
  const bool cpiv = (c >= p0 && c < p0 + MM);
  if (cpiv){
    if (tid < MM) temp[tid] = M[tid*67 + (c - p0)];
  } else {
    int k = tid >> 3, s8 = tid & 7;
    if (k < MM){
      double a = 0.0;
      for (int l = s8; l < MM; l += 8) a += M[k*67 + l]*srcMid[l];
      a += __shfl_xor(a, 1, 64);
      a += __shfl_xor(a, 2, 64);
      a += __shfl_xor(a, 4, 64);
      if (s8 == 0) temp[k] = a;
    }
  }
  __syncthreads();
  const int s = tid & 3;
  auto dorow = [&](int rr){
    if (rr >= p0 && rr < p0 + MM){
      if (s == 0){
        double val = temp[rr - p0];
        if (dstD) dstD[(size_t)rr*NSP + c] = val;
        else      dstF[perm258(rr)*NSP + perm258(c)] = (float)val;
      }
      return;
    }
    double acc = 0.0;
    for (int k = s; k < MM; k += 4) acc += src[(size_t)rr*NSP + p0 + k]*temp[k];
    acc += __shfl_xor(acc, 1, 64);
    acc += __shfl_xor(acc, 2, 64);
    if (s == 0){
      double f = cpiv ? 0.0 : src[(size_t)rr*NSP + c];
      double val = f - acc;
      if (dstD) dstD[(size_t)rr*NSP + c] = val;
      else      dstF[perm258(rr)*NSP + perm258(c)] = (float)val;
    }
  };
  { int r = tid >> 2; if (r < 256) dorow(r); }
  if (tid < 8) dorow(256 + (tid >> 2));
}

// =================== K2: persistent single-WG ADMM + softmax ===================
// 4 barriers/iter: R12 structure with ONLY the S2 fold merged into S3 (B2 removed).
// Consuming waves fold csTP redundantly (same op order -> bit-identical); S4a/B4/S4b kept.
__global__ __launch_bounds__(BLK) __attribute__((amdgpu_waves_per_eu(4, 4)))
void k_admm(const float* __restrict__ N32,
            const float* __restrict__ p32,
            const float* __restrict__ w32,
            float* __restrict__ out){
  __shared__ float2 tb[64][66];       // x^T staging for epilogue only
  __shared__ float2 csTP[64][18];     // col-sum partials (t, p*t) per (b, wave)
  __shared__ float  csX[64][20];      // col-sum partials of x per (b, wave)
  __shared__ __align__(16) float rsf[264];      // rs(pt) @64..127, rs(t) @192..255
  __shared__ float s2g[2];            // [0]=a_pg (row 256), [1]=a_g (row 257)
  __shared__ __align__(16) float s2p[4][264];   // matvec partials (fp32)
  __shared__ float2 pairB[64];        // (sbE, sbPE) per b
  __shared__ float2 pairR[64];        // (a_g + sF, a_pg + sPF) per a

  const int tid  = threadIdx.x;
  const int lane = tid & 63;          // b
  const int wvid = tid >> 6;          // wave -> rows a = 4*wvid..+3
  const int g    = tid >> 8;          // matvec jj-group (uniform per wave)
  const int c    = tid & 255;         // matvec column

  // ---- register cache of N column c (float4, fully static indexing) ----
  float4 nc4[16];
#pragma unroll
  for (int k2 = 0; k2 < 16; ++k2){
    nc4[k2].x = N32[(64*g + 4*k2 + 0)*NSP + c];
    nc4[k2].y = N32[(64*g + 4*k2 + 1)*NSP + c];
    nc4[k2].z = N32[(64*g + 4*k2 + 2)*NSP + c];
    nc4[k2].w = N32[(64*g + 4*k2 + 3)*NSP + c];
  }
  const float ncg0 = N32[256*NSP + c];
  const float ncg1 = N32[257*NSP + c];

  // tot-row cache for waves 4/5
  float nr0 = 0.f, nr1 = 0.f, nr2 = 0.f, nr3 = 0.f, nrt0 = 0.f, nrt1 = 0.f;
  if (wvid == 4 || wvid == 5){
    int r = 252 + wvid;   // 256 or 257
    nr0 = N32[r*NSP + lane];       nr1 = N32[r*NSP + lane + 64];
    nr2 = N32[r*NSP + lane + 128]; nr3 = N32[r*NSP + lane + 192];
    nrt0 = N32[r*NSP + 256];       nrt1 = N32[r*NSP + 257];
  }

  // which waves fold cs / totals redundantly in the merged matvec stage
  const bool foldCS = (g == 0) || (g == 2) || (wvid == 4) || (wvid == 5);
  const bool foldTT = (g == 0) || (wvid == 4) || (wvid == 5);

  // ---- state: fp32, f64 dual integrators ----
  float pr[4], wr[4], xr[4], vr[4], tq[4];
  double y2a[4], y2b = 0.0;
#pragma unroll
  for (int q = 0; q < 4; ++q){
    int j = (wvid*4 + q)*64 + lane;
    pr[q] = p32[j]; wr[q] = w32[j];
    xr[q] = 0.f; vr[q] = 0.f; tq[q] = 0.f; y2a[q] = 0.0;
  }
  __syncthreads();

  for (int it = 0; it < NITER; ++it){
    // ========== S1: y2b fold (4xb128), t = w*rhs, in-register row sums ==========
    if (it){
      float ybs = 0.f;
#pragma unroll
      for (int s = 0; s < 4; ++s){
        float4 v4 = *(const float4*)&csX[lane][4*s];
        ybs += (v4.x + v4.y) + (v4.z + v4.w);
      }
      y2b += RHO_ * ((double)ybs - 1.0);
    }
    float base = (float)(2.0*RHO_ - y2b);
    float clt = 0.f, clp = 0.f;
    float st0, st1, st2, st3, sp0, sp1, sp2, sp3;
#pragma unroll
    for (int q = 0; q < 4; ++q){
      float ya = (float)y2a[q];
      float rhs = 1e-3f*xr[q] + pr[q] + 100.f*fabsf(vr[q]) + base - ya;
      float t = wr[q]*rhs;
      float pt = pr[q]*t;
      tq[q] = t;
      clt += t; clp += pt;
      float st = wsum64u(t);
      float sp = wsum64u(pt);
      if (q == 0){ st0 = st; sp0 = sp; }
      else if (q == 1){ st1 = st; sp1 = sp; }
      else if (q == 2){ st2 = st; sp2 = sp; }
      else { st3 = st; sp3 = sp; }
    }
    csTP[lane][(wvid + lane) & 15] = make_float2(clt, clp);
    {
      int l2 = lane & 3;
      float sv_ = (l2 == 0) ? st0 : (l2 == 1) ? st1 : (l2 == 2) ? st2 : st3;
      float pv_ = (l2 == 0) ? sp0 : (l2 == 1) ? sp1 : (l2 == 2) ? sp2 : sp3;
      if (lane < 4)      rsf[192 + wvid*4 + l2] = sv_;   // rs(t)
      else if (lane < 8) rsf[64  + wvid*4 + l2] = pv_;   // rs(pt)
    }
    __syncthreads();  // B1

    // ========== S_M: redundant cs fold (consuming waves) + matvec ==========
    {
      float ct = 0.f, cp = 0.f, tt = 0.f, tp = 0.f;
      if (foldCS){
#pragma unroll
        for (int s = 0; s < 8; ++s){
          float4 v4 = *(const float4*)&csTP[lane][2*s];
          ct += v4.x + v4.z; cp += v4.y + v4.w;
        }
      }
      if (foldTT){
        tt = wsum64u(ct);   // tot(t)
        tp = wsum64u(cp);   // tot(pt)
      }
      float sv = (g == 0) ? cp : (g == 1) ? rsf[64 + lane]
               : (g == 2) ? ct : rsf[192 + lane];
      float a0 = 0.f, a1 = 0.f, a2 = 0.f, a3 = 0.f;
#pragma unroll
      for (int k2 = 0; k2 < 16; ++k2){
        float4 nq = nc4[k2];
        a0 += nq.x * __uint_as_float(__builtin_amdgcn_readlane(__float_as_uint(sv), 4*k2 + 0));
        a1 += nq.y * __uint_as_float(__builtin_amdgcn_readlane(__float_as_uint(sv), 4*k2 + 1));
        a2 += nq.z * __uint_as_float(__builtin_amdgcn_readlane(__float_as_uint(sv), 4*k2 + 2));
        a3 += nq.w * __uint_as_float(__builtin_amdgcn_readlane(__float_as_uint(sv), 4*k2 + 3));
      }
      float acc = (a0 + a1) + (a2 + a3);
      if (g == 0) acc += ncg0*tp + ncg1*tt;
      s2p[g][c] = acc;
      if (wvid == 4 || wvid == 5){
        float a32 = nr0*cp + nr1*rsf[lane + 64]
                  + nr2*ct + nr3*rsf[lane + 192];
        a32 = wsum64u(a32);
        if (lane == 0) s2g[wvid - 4] = a32 + nrt0*tp + nrt1*tt;
      }
    }
    __syncthreads();  // B2'

    // ========== S4a: fold into packed pairs (2 half-waves) ==========
    if (tid < 64){
      int b = tid;
      float sbE  = (s2p[0][128+b] + s2p[1][128+b]) + (s2p[2][128+b] + s2p[3][128+b]);
      float sbPE = (s2p[0][b] + s2p[1][b]) + (s2p[2][b] + s2p[3][b]);
      pairB[b] = make_float2(sbE, sbPE);
    } else if (tid < 128){
      int a = tid - 64;
      float sF  = (s2p[0][192+a] + s2p[1][192+a]) + (s2p[2][192+a] + s2p[3][192+a]);
      float sPF = (s2p[0][64+a] + s2p[1][64+a]) + (s2p[2][64+a] + s2p[3][64+a]);
      pairR[a] = make_float2(s2g[1] + sF, s2g[0] + sPF);
    }
    __syncthreads();  // B3'

    // ========== S4b: x update, v update, y2a, x col partials ==========
    {
      float2 pb = pairB[lane];
      float clx = 0.f;
#pragma unroll
      for (int q = 0; q < 4; ++q){
        int arow = wvid*4 + q;
        float2 prw = pairR[arow];
        float corr = prw.x + pb.x + pr[q]*(prw.y + pb.y);
        float xn = tq[q] - wr[q]*corr;
        vr[q] = xn + fminf(vr[q], 0.f);
        xr[q] = xn;
        float rsx = wsum64u(xn);
        y2a[q] += RHO_*((double)rsx - 1.0);
        clx += xn;
        if (it == NITER-1) ((float*)tb)[lane*68 + arow] = xn;   // x^T for epilogue
      }
      csX[lane][wvid] = clx;
    }
    __syncthreads();  // B4'
  }

  // ========== epilogue: clip + softmax(ALPHA*s, axis=-1) ==========
  const float* xb = (const float*)tb;
#pragma unroll
  for (int q = 0; q < 4; ++q){
    int i = wvid*4 + q;                 // n1 row index
    float val = xb[i*68 + lane];        // x[a=lane][b=i]
    val = fminf(fmaxf(val, 0.f), 1.f);
    float mx = wmax64f(val);
    float e = expf(200.f*(val - mx));
    float sm = wsum64f(e);
    out[i*64 + lane] = e / sm;
  }
}

extern "C" void kernel_launch(void* const* d_in, const int* in_sizes, int n_in,
                              void* d_out, int out_size, void* d_ws, size_t ws_size,
                              hipStream_t stream){
  (void)in_sizes; (void)n_in; (void)out_size; (void)ws_size;
  const float* ft  = (const float*)d_in[0];
  const float* fd  = (const float*)d_in[1];
  const float* iou = (const float*)d_in[2];
  const float* Wm  = (const float*)d_in[3];
  const float* bb  = (const float*)d_in[4];
  char* ws = (char*)d_ws;

  double* KsA  = (double*)(ws + OFF_KSA);
  double* KsB  = (double*)(ws + OFF_KSB);
  double* invG = (double*)(ws + OFF_INV);
  float*  N32  = (float*) (ws + OFF_N32);

  hipLaunchKernelGGL(kp_feat, dim3(NWG), dim3(BLK), 0, stream, ft, fd, iou, Wm, bb, ws);
  hipLaunchKernelGGL(kp_pw,   dim3(NWG), dim3(BLK), 0, stream, ws);
  hipLaunchKernelGGL(kp_sums, dim3(1),   dim3(BLK), 0, stream, ws);
  hipLaunchKernelGGL(kp_p3,   dim3(NS),  dim3(BLK), 0, stream, ws);

  hipLaunchKernelGGL(kp_inv<66>,   dim3(1),  dim3(BLK), 0, stream, KsB, 64, invG);
  hipLaunchKernelGGL(kp_apply<66>, dim3(NS), dim3(BLK), 0, stream, KsB, KsA, (float*)nullptr, 64, invG);
  hipLaunchKernelGGL(kp_inv<64>,   dim3(1),  dim3(BLK), 0, stream, KsA, 130, invG);
  hipLaunchKernelGGL(kp_apply<64>, dim3(NS), dim3(BLK), 0, stream, KsA, KsB, (float*)nullptr, 130, invG);
  hipLaunchKernelGGL(kp_inv<64>,   dim3(1),  dim3(BLK), 0, stream, KsB, 194, invG);
  hipLaunchKernelGGL(kp_apply<64>, dim3(NS), dim3(BLK), 0, stream, KsB, (double*)nullptr, N32, 194, invG);

  const float* p32 = (const float*)(ws + OFF_P32);
  const float* w32 = (const float*)(ws + OFF_W32);
  hipLaunchKernelGGL(k_admm, dim3(1), dim3(BLK), 0, stream, N32, p32, w32, (float*)d_out);
}